// Round 13
// baseline (568.100 us; speedup 1.0000x reference)
//
#include <hip/hip_runtime.h>
#include <cstdint>
#include <cstddef>

#define BNR 16384   // b*n rows
#define C   512     // feature dim
#define M   8192    // codebook size
#define BM  128
#define BN  128
#define BK  64
#define NCH 8       // K chunks = C/BK
#define NSETS 64    // column blocks (8192/128)

// tiled operand layout: [panel128][chunk8][kb8][row128][8 u16]
// per (panel,chunk) tile = 1024 units of 16B = 16 KiB; per panel = 128 KiB.
#define TILE_U16   8192      // u16 per (panel,chunk) tile
#define PANEL_U16  65536     // u16 per 128-row panel (8 chunks)

typedef float f32x4 __attribute__((ext_vector_type(4)));
typedef _Float16 f16x8 __attribute__((ext_vector_type(8)));
typedef unsigned short u16;

static __device__ __forceinline__ u16 h_bits(_Float16 h) {
    union { _Float16 h; u16 u; } x; x.h = h; return x.u;
}
static __device__ __forceinline__ void gl_lds16(const void* g, void* l) {
    __builtin_amdgcn_global_load_lds(
        (const __attribute__((address_space(1))) void*)g,
        (__attribute__((address_space(3))) void*)l, 16, 0, 0);
}

// ---------------- ||k||^2 per codebook row (exact fp32) ----------------
__global__ void knorm_k(const float* __restrict__ emb, float* __restrict__ knorm) {
    int gw   = (blockIdx.x * blockDim.x + threadIdx.x) >> 6;
    int lane = threadIdx.x & 63;
    int nw   = (gridDim.x * blockDim.x) >> 6;
    for (int row = gw; row < M; row += nw) {
        const float4* p = (const float4*)(emb + (size_t)row * C);
        float s = 0.f;
#pragma unroll
        for (int j = 0; j < 2; ++j) {
            float4 v = p[lane + 64 * j];
            s += v.x * v.x + v.y * v.y + v.z * v.z + v.w * v.w;
        }
#pragma unroll
        for (int o = 32; o > 0; o >>= 1) s += __shfl_down(s, o, 64);
        if (lane == 0) knorm[row] = s;
    }
}

// ---------------- fp32 -> fp16 hi, written in TILED layout ----------------
// One thread per 16B output unit, OUTPUT-linear (coalesced HBM writes).
// unit o: q=o&1023 -> kb=q>>7, row=q&127 ; chunk c=(o>>10)&7 ; panel=o>>13
__global__ void cvt_tile_k(const float* __restrict__ in, u16* __restrict__ outp) {
    int o = blockIdx.x * 256 + threadIdx.x;
    int q = o & 1023, kb = q >> 7, row = q & 127;
    int c = (o >> 10) & 7, pan = o >> 13;
    int grow = pan * BM + row;
    int k0 = c * BK + kb * 8;
    const float4* src = (const float4*)(in + (size_t)grow * C + k0);
    float4 a = src[0], b = src[1];
    u16 v[8] = { h_bits((_Float16)a.x), h_bits((_Float16)a.y),
                 h_bits((_Float16)a.z), h_bits((_Float16)a.w),
                 h_bits((_Float16)b.x), h_bits((_Float16)b.y),
                 h_bits((_Float16)b.z), h_bits((_Float16)b.w) };
    u16* dst = outp + (size_t)o * 8;
    *(ushort4*)(dst)     = *(ushort4*)(v);
    *(ushort4*)(dst + 4) = *(ushort4*)(v + 4);
}

// ---------------- MFMA distance GEMM + per-colblock top-2 ----------------
// m97 structure: 8192 blocks x 256 threads (4 waves, 2x2, 64x64/wave,
// acc[4][4]), single 32 KiB LDS buffer, 2 barriers per K-step, pre-tiled
// global operands -> gl_lds fully coalesced, LDS [kb][row][8] conflict-free.
// ~164 VGPR -> ~3 blocks/CU: inter-block overlap hides the barrier drain.
__global__ void mfma_argmin_k(
    const u16* __restrict__ x2t, const u16* __restrict__ e2t,
    const float* __restrict__ knorm,
    float* __restrict__ pv1, int* __restrict__ pi1,
    float* __restrict__ pv2, int* __restrict__ pi2) {
    __shared__ __align__(16) u16 ldsA[8][128][8];   // 16 KiB
    __shared__ __align__(16) u16 ldsB[8][128][8];   // 16 KiB

    const int tid  = threadIdx.x;
    const int lane = tid & 63;
    const int w    = tid >> 6;          // 0..3
    const int wm   = w >> 1, wn = w & 1;
    const int g    = lane >> 4, r = lane & 15;

    // bijective supertile XCD swizzle: supertile = 8rb x 8cb (64 blocks);
    // XCD gets 16 supertiles; concurrent window stays inside 4 MiB L2.
    const int xk = blockIdx.x & 7, j = blockIdx.x >> 3;
    const int stid = (j >> 6) * 8 + xk;      // 0..127
    const int p  = j & 63;
    const int rb = (stid & 15) * 8 + (p & 7);   // 0..127
    const int cb = (stid >> 4) * 8 + (p >> 3);  // 0..63
    const int rowBase = rb * BM, colBase = cb * BN;

    f32x4 acc[4][4];
#pragma unroll
    for (int m = 0; m < 4; ++m)
#pragma unroll
        for (int n = 0; n < 4; ++n) acc[m][n] = (f32x4)(0.0f);

    const u16* aT = x2t + (size_t)rb * PANEL_U16;
    const u16* bT = e2t + (size_t)cb * PANEL_U16;

#pragma unroll 1
    for (int c = 0; c < NCH; ++c) {
        if (c) __syncthreads();           // readers of previous tile done
#pragma unroll
        for (int it = 0; it < 4; ++it) {  // stage: 4 A-units + 4 B-units/thread
            int u = it * 256 + tid;
            gl_lds16(aT + (size_t)c * TILE_U16 + u * 8, (u16*)ldsA + u * 8);
            gl_lds16(bT + (size_t)c * TILE_U16 + u * 8, (u16*)ldsB + u * 8);
        }
        __syncthreads();                  // publishes DMA (vmcnt(0) implicit)

#pragma unroll
        for (int ks = 0; ks < 2; ++ks) {
            const int kb = ks * 4 + g;
            f16x8 a[4], b[4];
#pragma unroll
            for (int m = 0; m < 4; ++m)
                a[m] = *(const f16x8*)&ldsA[kb][wm * 64 + m * 16 + r][0];
#pragma unroll
            for (int n = 0; n < 4; ++n)
                b[n] = *(const f16x8*)&ldsB[kb][wn * 64 + n * 16 + r][0];
#pragma unroll
            for (int m = 0; m < 4; ++m)
#pragma unroll
                for (int n = 0; n < 4; ++n)
                    acc[m][n] = __builtin_amdgcn_mfma_f32_16x16x32_f16(
                        a[m], b[n], acc[m][n], 0, 0, 0);
        }
    }
    __syncthreads();   // last ds_reads retired before LDS reuse

    // ---- epilogue: per-row top-2 over this block's 128 cols ----
    float kn[4];
#pragma unroll
    for (int n = 0; n < 4; ++n) kn[n] = knorm[colBase + wn * 64 + n * 16 + r];

    float* mv = (float*)&ldsA[0][0][0];           // [2 wn][128 row][2]
    int*   mi = (int*)(mv + 2 * 128 * 2);         // 2 KiB + 2 KiB

#pragma unroll
    for (int m = 0; m < 4; ++m) {
#pragma unroll
        for (int q = 0; q < 4; ++q) {
            float v1 = 3.0e38f, v2 = 3.0e38f;
            int   i1 = 0x7fffffff, i2 = 0x7fffffff;
#pragma unroll
            for (int n = 0; n < 4; ++n) {
                int col = colBase + wn * 64 + n * 16 + r;
                float d = fmaf(-2.0f, acc[m][n][q], kn[n]);
                if (d < v1 || (d == v1 && col < i1)) {
                    v2 = v1; i2 = i1; v1 = d; i1 = col;
                } else if (d < v2 || (d == v2 && col < i2)) {
                    v2 = d; i2 = col;
                }
            }
#pragma unroll
            for (int msk = 1; msk < 16; msk <<= 1) {
                float ov1 = __shfl_xor(v1, msk, 64);
                int   oi1 = __shfl_xor(i1, msk, 64);
                float ov2 = __shfl_xor(v2, msk, 64);
                int   oi2 = __shfl_xor(i2, msk, 64);
                bool ob = (ov1 < v1) || (ov1 == v1 && oi1 < i1);
                float nbv = ob ? ov1 : v1;  int nbi = ob ? oi1 : i1;
                float c1v = ob ? ov2 : v2;  int c1i = ob ? oi2 : i2;
                float c2v = ob ? v1 : ov1;  int c2i = ob ? i1 : oi1;
                bool cb2 = (c2v < c1v) || (c2v == c1v && c2i < c1i);
                v1 = nbv; i1 = nbi;
                v2 = cb2 ? c2v : c1v; i2 = cb2 ? c2i : c1i;
            }
            if (r == 0) {
                int lrow = wm * 64 + m * 16 + g * 4 + q;   // 0..127
                mv[(wn * 128 + lrow) * 2 + 0] = v1;
                mv[(wn * 128 + lrow) * 2 + 1] = v2;
                mi[(wn * 128 + lrow) * 2 + 0] = i1;
                mi[(wn * 128 + lrow) * 2 + 1] = i2;
            }
        }
    }
    __syncthreads();

    // merge 2 wn-halves' top-2 -> per-row top-2 over 128 cols
    if (tid < 128) {
        float V1 = 3.0e38f, V2 = 3.0e38f;
        int   I1 = 0x7fffffff, I2 = 0x7fffffff;
#pragma unroll
        for (int s = 0; s < 4; ++s) {
            float d = mv[((s >> 1) * 128 + tid) * 2 + (s & 1)];
            int   ci = mi[((s >> 1) * 128 + tid) * 2 + (s & 1)];
            if (d < V1 || (d == V1 && ci < I1)) {
                V2 = V1; I2 = I1; V1 = d; I1 = ci;
            } else if (d < V2 || (d == V2 && ci < I2)) {
                V2 = d; I2 = ci;
            }
        }
        size_t o = (size_t)cb * BNR + rowBase + tid;
        pv1[o] = V1; pi1[o] = I1;
        pv2[o] = V2; pi2[o] = I2;
    }
}

// ---------------- refine: top-8 of 128 candidates, exact fp64 ----------------
// block 256 = 4 waves = 4 rows; lane l holds set l's {top1, top2}.
__global__ void refine_k(const float* __restrict__ x, const float* __restrict__ emb,
                         const float* __restrict__ pv1, const int* __restrict__ pi1,
                         const float* __restrict__ pv2, const int* __restrict__ pi2,
                         float* __restrict__ out_idx) {
    int row  = blockIdx.x * 4 + (threadIdx.x >> 6);
    int lane = threadIdx.x & 63;
    size_t off = (size_t)lane * BNR + row;
    float va = pv1[off]; int ia = pi1[off];
    float vb = pv2[off]; int ib = pi2[off];
    int cand[8];
#pragma unroll
    for (int b = 0; b < 8; ++b) {
        bool al = (va < vb) || (va == vb && ia < ib);
        float cv = al ? va : vb; int ci = al ? ia : ib;
#pragma unroll
        for (int msk = 1; msk < 64; msk <<= 1) {
            float ov = __shfl_xor(cv, msk, 64);
            int   oi = __shfl_xor(ci, msk, 64);
            if (ov < cv || (ov == cv && oi < ci)) { cv = ov; ci = oi; }
        }
        cand[b] = ci;
        // indices are globally unique -> invalidate by index
        if (ia == ci) va = 3.0e38f;
        else if (ib == ci) vb = 3.0e38f;
    }
    int gid = lane >> 3, gl = lane & 7;
    int myc = cand[gid];
    const float* qp = x + (size_t)row * C;
    const float* kp = emb + (size_t)myc * C;
    double s = 0.0;
#pragma unroll 4
    for (int j = gl * 64; j < gl * 64 + 64; j += 4) {
        float4 q4 = *(const float4*)(qp + j);
        float4 k4 = *(const float4*)(kp + j);
        double d0 = (double)q4.x - (double)k4.x;
        double d1 = (double)q4.y - (double)k4.y;
        double d2 = (double)q4.z - (double)k4.z;
        double d3 = (double)q4.w - (double)k4.w;
        s += d0 * d0 + d1 * d1 + d2 * d2 + d3 * d3;
    }
    s += __shfl_xor(s, 1, 64);
    s += __shfl_xor(s, 2, 64);
    s += __shfl_xor(s, 4, 64);
    double dv = (gl == 0) ? s : 1.0e300;
    int    di = (gl == 0) ? myc : 0x7fffffff;
#pragma unroll
    for (int msk = 8; msk < 64; msk <<= 1) {
        double ov = __shfl_xor(dv, msk, 64);
        int    oi = __shfl_xor(di, msk, 64);
        if (ov < dv || (ov == dv && oi < di)) { dv = ov; di = oi; }
    }
    if (lane == 0) out_idx[row] = (float)di;
}

// ---------------- fused onehot zero+scatter + z_st gather ----------------
// One block per row. Streams the row's 8192-float onehot (zeros + 1.0 at idx)
// as float4 stores, and gathers the 512-float codebook row into z_st.
// Replaces hipMemsetAsync (1.55 TB/s rocclr fill) + gather_k.
__global__ void onehot_gather_k(const float* __restrict__ emb,
                                const float* __restrict__ out_idx,
                                float* __restrict__ zst,
                                float* __restrict__ onehot) {
    const int row = blockIdx.x;
    const int tid = threadIdx.x;
    const int idx = (int)out_idx[row];

    // z_st row: 128 float4
    if (tid < 128) {
        const float4* src = (const float4*)(emb + (size_t)idx * C);
        float4* dst = (float4*)(zst + (size_t)row * C);
        dst[tid] = src[tid];
    }

    // onehot row: 2048 float4, 8 per thread
    float4* orow = (float4*)(onehot + (size_t)row * M);
    const int hot4 = idx >> 2, hotc = idx & 3;
#pragma unroll
    for (int t = 0; t < 8; ++t) {
        int j4 = tid * 8 + t;
        float4 v = (float4){0.f, 0.f, 0.f, 0.f};
        if (j4 == hot4) {
            if (hotc == 0) v.x = 1.0f;
            else if (hotc == 1) v.y = 1.0f;
            else if (hotc == 2) v.z = 1.0f;
            else v.w = 1.0f;
        }
        orow[j4] = v;
    }
}

// ---------------- perplexity via LDS histogram ----------------
__global__ void perp_k(const float* __restrict__ out_idx, float* __restrict__ out_perp) {
    __shared__ int hist[M];
    __shared__ float red[256];
    int tid = threadIdx.x;
    for (int j = tid; j < M; j += 256) hist[j] = 0;
    __syncthreads();
    for (int j = tid; j < BNR; j += 256) atomicAdd(&hist[(int)out_idx[j]], 1);
    __syncthreads();
    float s = 0.f;
    for (int j = tid; j < M; j += 256) {
        float pb = (float)hist[j] * (1.0f / (float)BNR);
        s += pb * logf(pb + 1e-10f);
    }
    red[tid] = s; __syncthreads();
    for (int o = 128; o > 0; o >>= 1) {
        if (tid < o) red[tid] += red[tid + o];
        __syncthreads();
    }
    if (tid == 0) out_perp[0] = expf(-red[0]);
}

extern "C" void kernel_launch(void* const* d_in, const int* in_sizes, int n_in,
                              void* d_out, int out_size, void* d_ws, size_t ws_size,
                              hipStream_t stream) {
    const float* x   = (const float*)d_in[0];
    const float* emb = (const float*)d_in[1];

    float* out        = (float*)d_out;
    float* out_zst    = out;                              // 8388608
    float* out_idx    = out + (size_t)BNR * C;            // 16384
    float* out_onehot = out_idx + BNR;                    // 134217728
    float* out_perp   = out_onehot + (size_t)BNR * M;     // 1

    // scratch lives in the onehot region (overwritten by onehot_gather_k):
    u16*   x2t   = (u16*)out_onehot;                      // 16 MiB (tiled)
    u16*   e2t   = x2t + (size_t)BNR * C;                 // 8 MiB  (tiled)
    float* knorm = (float*)(e2t + (size_t)M * C);
    float* pv1   = knorm + M;                             // 4 MiB each
    float* pv2   = pv1 + (size_t)NSETS * BNR;
    int*   pi1   = (int*)(pv2 + (size_t)NSETS * BNR);
    int*   pi2   = pi1 + (size_t)NSETS * BNR;

    cvt_tile_k<<<(BNR * C / 8) / 256, 256, 0, stream>>>(x, x2t);
    cvt_tile_k<<<(M * C / 8) / 256, 256, 0, stream>>>(emb, e2t);
    knorm_k<<<64, 256, 0, stream>>>(emb, knorm);
    mfma_argmin_k<<<(BNR / BM) * (M / BN), 256, 0, stream>>>(
        x2t, e2t, knorm, pv1, pi1, pv2, pi2);
    refine_k<<<BNR / 4, 256, 0, stream>>>(x, emb, pv1, pi1, pv2, pi2, out_idx);
    onehot_gather_k<<<BNR, 256, 0, stream>>>(emb, out_idx, out_zst, out_onehot);
    perp_k<<<1, 256, 0, stream>>>(out_idx, out_perp);
}

// Round 14
// 488.858 us; speedup vs baseline: 1.1621x; 1.1621x over previous
//
#include <hip/hip_runtime.h>
#include <cstdint>
#include <cstddef>

#define BNR 16384   // b*n rows
#define C   512     // feature dim
#define M   8192    // codebook size
#define BM  128
#define BN  128
#define BK  64
#define NCH 8       // K chunks = C/BK
#define NSETS 64    // column blocks (8192/128)

// tiled operand layout: [panel128][chunk8][kb8][row128][8 u16]
// per (panel,chunk) tile = 1024 units of 16B = 16 KiB; per panel = 128 KiB.
#define TILE_U16   8192      // u16 per (panel,chunk) tile
#define PANEL_U16  65536     // u16 per 128-row panel (8 chunks)

typedef float f32x4 __attribute__((ext_vector_type(4)));
typedef _Float16 f16x8 __attribute__((ext_vector_type(8)));
typedef unsigned short u16;

static __device__ __forceinline__ u16 h_bits(_Float16 h) {
    union { _Float16 h; u16 u; } x; x.h = h; return x.u;
}
static __device__ __forceinline__ void gl_lds16(const void* g, void* l) {
    __builtin_amdgcn_global_load_lds(
        (const __attribute__((address_space(1))) void*)g,
        (__attribute__((address_space(3))) void*)l, 16, 0, 0);
}

// ---------------- ||k||^2 per codebook row (exact fp32) ----------------
__global__ void knorm_k(const float* __restrict__ emb, float* __restrict__ knorm) {
    int gw   = (blockIdx.x * blockDim.x + threadIdx.x) >> 6;
    int lane = threadIdx.x & 63;
    int nw   = (gridDim.x * blockDim.x) >> 6;
    for (int row = gw; row < M; row += nw) {
        const float4* p = (const float4*)(emb + (size_t)row * C);
        float s = 0.f;
#pragma unroll
        for (int j = 0; j < 2; ++j) {
            float4 v = p[lane + 64 * j];
            s += v.x * v.x + v.y * v.y + v.z * v.z + v.w * v.w;
        }
#pragma unroll
        for (int o = 32; o > 0; o >>= 1) s += __shfl_down(s, o, 64);
        if (lane == 0) knorm[row] = s;
    }
}

// ---------------- fp32 -> fp16 hi, written in TILED layout ----------------
// One thread per 16B output unit, OUTPUT-linear (coalesced HBM writes).
// unit o: q=o&1023 -> kb=q>>7, row=q&127 ; chunk c=(o>>10)&7 ; panel=o>>13
__global__ void cvt_tile_k(const float* __restrict__ in, u16* __restrict__ outp) {
    int o = blockIdx.x * 256 + threadIdx.x;
    int q = o & 1023, kb = q >> 7, row = q & 127;
    int c = (o >> 10) & 7, pan = o >> 13;
    int grow = pan * BM + row;
    int k0 = c * BK + kb * 8;
    const float4* src = (const float4*)(in + (size_t)grow * C + k0);
    float4 a = src[0], b = src[1];
    u16 v[8] = { h_bits((_Float16)a.x), h_bits((_Float16)a.y),
                 h_bits((_Float16)a.z), h_bits((_Float16)a.w),
                 h_bits((_Float16)b.x), h_bits((_Float16)b.y),
                 h_bits((_Float16)b.z), h_bits((_Float16)b.w) };
    u16* dst = outp + (size_t)o * 8;
    *(ushort4*)(dst)     = *(ushort4*)(v);
    *(ushort4*)(dst + 4) = *(ushort4*)(v + 4);
}

// ---------------- MFMA distance GEMM + per-colblock top-2 ----------------
// m97 structure: 8192 blocks x 256 threads (4 waves, 2x2, 64x64/wave,
// acc[4][4]), single 32 KiB LDS buffer, 2 barriers per K-step, pre-tiled
// global operands -> gl_lds fully coalesced, LDS [kb][row][8] conflict-free.
__global__ void mfma_argmin_k(
    const u16* __restrict__ x2t, const u16* __restrict__ e2t,
    const float* __restrict__ knorm,
    float* __restrict__ pv1, int* __restrict__ pi1,
    float* __restrict__ pv2, int* __restrict__ pi2) {
    __shared__ __align__(16) u16 ldsA[8][128][8];   // 16 KiB
    __shared__ __align__(16) u16 ldsB[8][128][8];   // 16 KiB

    const int tid  = threadIdx.x;
    const int lane = tid & 63;
    const int w    = tid >> 6;          // 0..3
    const int wm   = w >> 1, wn = w & 1;
    const int g    = lane >> 4, r = lane & 15;

    // bijective supertile XCD swizzle: supertile = 8rb x 8cb (64 blocks);
    // XCD gets 16 supertiles; concurrent window stays inside 4 MiB L2.
    const int xk = blockIdx.x & 7, j = blockIdx.x >> 3;
    const int stid = (j >> 6) * 8 + xk;      // 0..127
    const int p  = j & 63;
    const int rb = (stid & 15) * 8 + (p & 7);   // 0..127
    const int cb = (stid >> 4) * 8 + (p >> 3);  // 0..63
    const int rowBase = rb * BM, colBase = cb * BN;

    f32x4 acc[4][4];
#pragma unroll
    for (int m = 0; m < 4; ++m)
#pragma unroll
        for (int n = 0; n < 4; ++n) acc[m][n] = (f32x4)(0.0f);

    const u16* aT = x2t + (size_t)rb * PANEL_U16;
    const u16* bT = e2t + (size_t)cb * PANEL_U16;

#pragma unroll 1
    for (int c = 0; c < NCH; ++c) {
        if (c) __syncthreads();           // readers of previous tile done
#pragma unroll
        for (int it = 0; it < 4; ++it) {  // stage: 4 A-units + 4 B-units/thread
            int u = it * 256 + tid;
            gl_lds16(aT + (size_t)c * TILE_U16 + u * 8, (u16*)ldsA + u * 8);
            gl_lds16(bT + (size_t)c * TILE_U16 + u * 8, (u16*)ldsB + u * 8);
        }
        __syncthreads();                  // publishes DMA (vmcnt(0) implicit)

#pragma unroll
        for (int ks = 0; ks < 2; ++ks) {
            const int kb = ks * 4 + g;
            f16x8 a[4], b[4];
#pragma unroll
            for (int m = 0; m < 4; ++m)
                a[m] = *(const f16x8*)&ldsA[kb][wm * 64 + m * 16 + r][0];
#pragma unroll
            for (int n = 0; n < 4; ++n)
                b[n] = *(const f16x8*)&ldsB[kb][wn * 64 + n * 16 + r][0];
#pragma unroll
            for (int m = 0; m < 4; ++m)
#pragma unroll
                for (int n = 0; n < 4; ++n)
                    acc[m][n] = __builtin_amdgcn_mfma_f32_16x16x32_f16(
                        a[m], b[n], acc[m][n], 0, 0, 0);
        }
    }
    __syncthreads();   // last ds_reads retired before LDS reuse

    // ---- epilogue: per-row top-2 over this block's 128 cols ----
    float kn[4];
#pragma unroll
    for (int n = 0; n < 4; ++n) kn[n] = knorm[colBase + wn * 64 + n * 16 + r];

    float* mv = (float*)&ldsA[0][0][0];           // [2 wn][128 row][2]
    int*   mi = (int*)(mv + 2 * 128 * 2);         // 2 KiB + 2 KiB

#pragma unroll
    for (int m = 0; m < 4; ++m) {
#pragma unroll
        for (int q = 0; q < 4; ++q) {
            float v1 = 3.0e38f, v2 = 3.0e38f;
            int   i1 = 0x7fffffff, i2 = 0x7fffffff;
#pragma unroll
            for (int n = 0; n < 4; ++n) {
                int col = colBase + wn * 64 + n * 16 + r;
                float d = fmaf(-2.0f, acc[m][n][q], kn[n]);
                if (d < v1 || (d == v1 && col < i1)) {
                    v2 = v1; i2 = i1; v1 = d; i1 = col;
                } else if (d < v2 || (d == v2 && col < i2)) {
                    v2 = d; i2 = col;
                }
            }
#pragma unroll
            for (int msk = 1; msk < 16; msk <<= 1) {
                float ov1 = __shfl_xor(v1, msk, 64);
                int   oi1 = __shfl_xor(i1, msk, 64);
                float ov2 = __shfl_xor(v2, msk, 64);
                int   oi2 = __shfl_xor(i2, msk, 64);
                bool ob = (ov1 < v1) || (ov1 == v1 && oi1 < i1);
                float nbv = ob ? ov1 : v1;  int nbi = ob ? oi1 : i1;
                float c1v = ob ? ov2 : v2;  int c1i = ob ? oi2 : i2;
                float c2v = ob ? v1 : ov1;  int c2i = ob ? i1 : oi1;
                bool cb2 = (c2v < c1v) || (c2v == c1v && c2i < c1i);
                v1 = nbv; i1 = nbi;
                v2 = cb2 ? c2v : c1v; i2 = cb2 ? c2i : c1i;
            }
            if (r == 0) {
                int lrow = wm * 64 + m * 16 + g * 4 + q;   // 0..127
                mv[(wn * 128 + lrow) * 2 + 0] = v1;
                mv[(wn * 128 + lrow) * 2 + 1] = v2;
                mi[(wn * 128 + lrow) * 2 + 0] = i1;
                mi[(wn * 128 + lrow) * 2 + 1] = i2;
            }
        }
    }
    __syncthreads();

    // merge 2 wn-halves' top-2 -> per-row top-2 over 128 cols
    if (tid < 128) {
        float V1 = 3.0e38f, V2 = 3.0e38f;
        int   I1 = 0x7fffffff, I2 = 0x7fffffff;
#pragma unroll
        for (int s = 0; s < 4; ++s) {
            float d = mv[((s >> 1) * 128 + tid) * 2 + (s & 1)];
            int   ci = mi[((s >> 1) * 128 + tid) * 2 + (s & 1)];
            if (d < V1 || (d == V1 && ci < I1)) {
                V2 = V1; I2 = I1; V1 = d; I1 = ci;
            } else if (d < V2 || (d == V2 && ci < I2)) {
                V2 = d; I2 = ci;
            }
        }
        size_t o = (size_t)cb * BNR + rowBase + tid;
        pv1[o] = V1; pi1[o] = I1;
        pv2[o] = V2; pi2[o] = I2;
    }
}

// ---------------- refine: top-8 of 128 candidates, exact fp64 ----------------
// block 256 = 4 waves = 4 rows; lane l holds set l's {top1, top2}.
__global__ void refine_k(const float* __restrict__ x, const float* __restrict__ emb,
                         const float* __restrict__ pv1, const int* __restrict__ pi1,
                         const float* __restrict__ pv2, const int* __restrict__ pi2,
                         float* __restrict__ out_idx) {
    int row  = blockIdx.x * 4 + (threadIdx.x >> 6);
    int lane = threadIdx.x & 63;
    size_t off = (size_t)lane * BNR + row;
    float va = pv1[off]; int ia = pi1[off];
    float vb = pv2[off]; int ib = pi2[off];
    int cand[8];
#pragma unroll
    for (int b = 0; b < 8; ++b) {
        bool al = (va < vb) || (va == vb && ia < ib);
        float cv = al ? va : vb; int ci = al ? ia : ib;
#pragma unroll
        for (int msk = 1; msk < 64; msk <<= 1) {
            float ov = __shfl_xor(cv, msk, 64);
            int   oi = __shfl_xor(ci, msk, 64);
            if (ov < cv || (ov == cv && oi < ci)) { cv = ov; ci = oi; }
        }
        cand[b] = ci;
        // indices are globally unique -> invalidate by index
        if (ia == ci) va = 3.0e38f;
        else if (ib == ci) vb = 3.0e38f;
    }
    int gid = lane >> 3, gl = lane & 7;
    int myc = cand[gid];
    const float* qp = x + (size_t)row * C;
    const float* kp = emb + (size_t)myc * C;
    double s = 0.0;
#pragma unroll 4
    for (int j = gl * 64; j < gl * 64 + 64; j += 4) {
        float4 q4 = *(const float4*)(qp + j);
        float4 k4 = *(const float4*)(kp + j);
        double d0 = (double)q4.x - (double)k4.x;
        double d1 = (double)q4.y - (double)k4.y;
        double d2 = (double)q4.z - (double)k4.z;
        double d3 = (double)q4.w - (double)k4.w;
        s += d0 * d0 + d1 * d1 + d2 * d2 + d3 * d3;
    }
    s += __shfl_xor(s, 1, 64);
    s += __shfl_xor(s, 2, 64);
    s += __shfl_xor(s, 4, 64);
    double dv = (gl == 0) ? s : 1.0e300;
    int    di = (gl == 0) ? myc : 0x7fffffff;
#pragma unroll
    for (int msk = 8; msk < 64; msk <<= 1) {
        double ov = __shfl_xor(dv, msk, 64);
        int    oi = __shfl_xor(di, msk, 64);
        if (ov < dv || (ov == dv && oi < di)) { dv = ov; di = oi; }
    }
    if (lane == 0) out_idx[row] = (float)di;
}

// ---------------- fused onehot zero+scatter + z_st gather ----------------
// One block per row. COALESCED store map: iteration t writes float4 index
// j4 = t*256 + tid -> each wave stores 1 KiB contiguous per instruction.
__global__ void onehot_gather_k(const float* __restrict__ emb,
                                const float* __restrict__ out_idx,
                                float* __restrict__ zst,
                                float* __restrict__ onehot) {
    const int row = blockIdx.x;
    const int tid = threadIdx.x;
    const int idx = (int)out_idx[row];

    // z_st row: 128 float4
    if (tid < 128) {
        const float4* src = (const float4*)(emb + (size_t)idx * C);
        float4* dst = (float4*)(zst + (size_t)row * C);
        dst[tid] = src[tid];
    }

    // onehot row: 2048 float4, coalesced across threads
    float4* orow = (float4*)(onehot + (size_t)row * M);
    const int hot4 = idx >> 2, hotc = idx & 3;
#pragma unroll
    for (int t = 0; t < 8; ++t) {
        int j4 = t * 256 + tid;
        float4 v = (float4){0.f, 0.f, 0.f, 0.f};
        if (j4 == hot4) {
            if (hotc == 0) v.x = 1.0f;
            else if (hotc == 1) v.y = 1.0f;
            else if (hotc == 2) v.z = 1.0f;
            else v.w = 1.0f;
        }
        orow[j4] = v;
    }
}

// ---------------- perplexity via LDS histogram ----------------
__global__ void perp_k(const float* __restrict__ out_idx, float* __restrict__ out_perp) {
    __shared__ int hist[M];
    __shared__ float red[256];
    int tid = threadIdx.x;
    for (int j = tid; j < M; j += 256) hist[j] = 0;
    __syncthreads();
    for (int j = tid; j < BNR; j += 256) atomicAdd(&hist[(int)out_idx[j]], 1);
    __syncthreads();
    float s = 0.f;
    for (int j = tid; j < M; j += 256) {
        float pb = (float)hist[j] * (1.0f / (float)BNR);
        s += pb * logf(pb + 1e-10f);
    }
    red[tid] = s; __syncthreads();
    for (int o = 128; o > 0; o >>= 1) {
        if (tid < o) red[tid] += red[tid + o];
        __syncthreads();
    }
    if (tid == 0) out_perp[0] = expf(-red[0]);
}

extern "C" void kernel_launch(void* const* d_in, const int* in_sizes, int n_in,
                              void* d_out, int out_size, void* d_ws, size_t ws_size,
                              hipStream_t stream) {
    const float* x   = (const float*)d_in[0];
    const float* emb = (const float*)d_in[1];

    float* out        = (float*)d_out;
    float* out_zst    = out;                              // 8388608
    float* out_idx    = out + (size_t)BNR * C;            // 16384
    float* out_onehot = out_idx + BNR;                    // 134217728
    float* out_perp   = out_onehot + (size_t)BNR * M;     // 1

    // scratch lives in the onehot region (overwritten by onehot_gather_k):
    u16*   x2t   = (u16*)out_onehot;                      // 16 MiB (tiled)
    u16*   e2t   = x2t + (size_t)BNR * C;                 // 8 MiB  (tiled)
    float* knorm = (float*)(e2t + (size_t)M * C);
    float* pv1   = knorm + M;                             // 4 MiB each
    float* pv2   = pv1 + (size_t)NSETS * BNR;
    int*   pi1   = (int*)(pv2 + (size_t)NSETS * BNR);
    int*   pi2   = pi1 + (size_t)NSETS * BNR;

    cvt_tile_k<<<(BNR * C / 8) / 256, 256, 0, stream>>>(x, x2t);
    cvt_tile_k<<<(M * C / 8) / 256, 256, 0, stream>>>(emb, e2t);
    knorm_k<<<64, 256, 0, stream>>>(emb, knorm);
    mfma_argmin_k<<<(BNR / BM) * (M / BN), 256, 0, stream>>>(
        x2t, e2t, knorm, pv1, pi1, pv2, pi2);
    refine_k<<<BNR / 4, 256, 0, stream>>>(x, emb, pv1, pi1, pv2, pi2, out_idx);
    onehot_gather_k<<<BNR, 256, 0, stream>>>(emb, out_idx, out_zst, out_onehot);
    perp_k<<<1, 256, 0, stream>>>(out_idx, out_perp);
}

// Round 15
// 479.442 us; speedup vs baseline: 1.1849x; 1.0196x over previous
//
#include <hip/hip_runtime.h>
#include <cstdint>
#include <cstddef>

#define BNR 16384   // b*n rows
#define C   512     // feature dim
#define M   8192    // codebook size
#define BM  128
#define BN  128
#define BK  64
#define NCH 8       // K chunks = C/BK
#define NSETS 64    // column blocks (8192/128)

// tiled operand layout: [panel128][chunk8][kb8][row128][8 u16]
// per (panel,chunk) tile = 1024 units of 16B = 16 KiB; per panel = 128 KiB.
#define TILE_U16   8192      // u16 per (panel,chunk) tile
#define PANEL_U16  65536     // u16 per 128-row panel (8 chunks)

typedef float f32x4 __attribute__((ext_vector_type(4)));
typedef _Float16 f16x8 __attribute__((ext_vector_type(8)));
typedef unsigned short u16;

static __device__ __forceinline__ u16 h_bits(_Float16 h) {
    union { _Float16 h; u16 u; } x; x.h = h; return x.u;
}
static __device__ __forceinline__ void gl_lds16(const void* g, void* l) {
    __builtin_amdgcn_global_load_lds(
        (const __attribute__((address_space(1))) void*)g,
        (__attribute__((address_space(3))) void*)l, 16, 0, 0);
}

// ---------------- ||k||^2 per codebook row (exact fp32) ----------------
__global__ void knorm_k(const float* __restrict__ emb, float* __restrict__ knorm) {
    int gw   = (blockIdx.x * blockDim.x + threadIdx.x) >> 6;
    int lane = threadIdx.x & 63;
    int nw   = (gridDim.x * blockDim.x) >> 6;
    for (int row = gw; row < M; row += nw) {
        const float4* p = (const float4*)(emb + (size_t)row * C);
        float s = 0.f;
#pragma unroll
        for (int j = 0; j < 2; ++j) {
            float4 v = p[lane + 64 * j];
            s += v.x * v.x + v.y * v.y + v.z * v.z + v.w * v.w;
        }
#pragma unroll
        for (int o = 32; o > 0; o >>= 1) s += __shfl_down(s, o, 64);
        if (lane == 0) knorm[row] = s;
    }
}

// ---------------- fp32 -> fp16 hi, written in TILED layout ----------------
// One thread per 16B output unit, OUTPUT-linear (coalesced HBM writes).
// unit o: q=o&1023 -> kb=q>>7, row=q&127 ; chunk c=(o>>10)&7 ; panel=o>>13
__global__ void cvt_tile_k(const float* __restrict__ in, u16* __restrict__ outp) {
    int o = blockIdx.x * 256 + threadIdx.x;
    int q = o & 1023, kb = q >> 7, row = q & 127;
    int c = (o >> 10) & 7, pan = o >> 13;
    int grow = pan * BM + row;
    int k0 = c * BK + kb * 8;
    const float4* src = (const float4*)(in + (size_t)grow * C + k0);
    float4 a = src[0], b = src[1];
    u16 v[8] = { h_bits((_Float16)a.x), h_bits((_Float16)a.y),
                 h_bits((_Float16)a.z), h_bits((_Float16)a.w),
                 h_bits((_Float16)b.x), h_bits((_Float16)b.y),
                 h_bits((_Float16)b.z), h_bits((_Float16)b.w) };
    u16* dst = outp + (size_t)o * 8;
    *(ushort4*)(dst)     = *(ushort4*)(v);
    *(ushort4*)(dst + 4) = *(ushort4*)(v + 4);
}

// ---------------- MFMA distance GEMM + per-colblock top-2 ----------------
// m97 structure: 8192 blocks x 256 threads (4 waves, 2x2, 64x64/wave,
// acc[4][4]), single 32 KiB LDS buffer, 2 barriers per K-step, pre-tiled
// global operands -> gl_lds fully coalesced, LDS [kb][row][8] conflict-free.
__global__ void mfma_argmin_k(
    const u16* __restrict__ x2t, const u16* __restrict__ e2t,
    const float* __restrict__ knorm,
    float* __restrict__ pv1, int* __restrict__ pi1,
    float* __restrict__ pv2, int* __restrict__ pi2) {
    __shared__ __align__(16) u16 ldsA[8][128][8];   // 16 KiB
    __shared__ __align__(16) u16 ldsB[8][128][8];   // 16 KiB

    const int tid  = threadIdx.x;
    const int lane = tid & 63;
    const int w    = tid >> 6;          // 0..3
    const int wm   = w >> 1, wn = w & 1;
    const int g    = lane >> 4, r = lane & 15;

    // bijective supertile XCD swizzle: supertile = 8rb x 8cb (64 blocks);
    // XCD gets 16 supertiles; concurrent window stays inside 4 MiB L2.
    const int xk = blockIdx.x & 7, j = blockIdx.x >> 3;
    const int stid = (j >> 6) * 8 + xk;      // 0..127
    const int p  = j & 63;
    const int rb = (stid & 15) * 8 + (p & 7);   // 0..127
    const int cb = (stid >> 4) * 8 + (p >> 3);  // 0..63
    const int rowBase = rb * BM, colBase = cb * BN;

    f32x4 acc[4][4];
#pragma unroll
    for (int m = 0; m < 4; ++m)
#pragma unroll
        for (int n = 0; n < 4; ++n) acc[m][n] = (f32x4)(0.0f);

    const u16* aT = x2t + (size_t)rb * PANEL_U16;
    const u16* bT = e2t + (size_t)cb * PANEL_U16;

#pragma unroll 1
    for (int c = 0; c < NCH; ++c) {
        if (c) __syncthreads();           // readers of previous tile done
#pragma unroll
        for (int it = 0; it < 4; ++it) {  // stage: 4 A-units + 4 B-units/thread
            int u = it * 256 + tid;
            gl_lds16(aT + (size_t)c * TILE_U16 + u * 8, (u16*)ldsA + u * 8);
            gl_lds16(bT + (size_t)c * TILE_U16 + u * 8, (u16*)ldsB + u * 8);
        }
        __syncthreads();                  // publishes DMA (vmcnt(0) implicit)

#pragma unroll
        for (int ks = 0; ks < 2; ++ks) {
            const int kb = ks * 4 + g;
            f16x8 a[4], b[4];
#pragma unroll
            for (int m = 0; m < 4; ++m)
                a[m] = *(const f16x8*)&ldsA[kb][wm * 64 + m * 16 + r][0];
#pragma unroll
            for (int n = 0; n < 4; ++n)
                b[n] = *(const f16x8*)&ldsB[kb][wn * 64 + n * 16 + r][0];
#pragma unroll
            for (int m = 0; m < 4; ++m)
#pragma unroll
                for (int n = 0; n < 4; ++n)
                    acc[m][n] = __builtin_amdgcn_mfma_f32_16x16x32_f16(
                        a[m], b[n], acc[m][n], 0, 0, 0);
        }
    }
    __syncthreads();   // last ds_reads retired before LDS reuse

    // ---- epilogue: per-row top-2 over this block's 128 cols ----
    float kn[4];
#pragma unroll
    for (int n = 0; n < 4; ++n) kn[n] = knorm[colBase + wn * 64 + n * 16 + r];

    float* mv = (float*)&ldsA[0][0][0];           // [2 wn][128 row][2]
    int*   mi = (int*)(mv + 2 * 128 * 2);         // 2 KiB + 2 KiB

#pragma unroll
    for (int m = 0; m < 4; ++m) {
#pragma unroll
        for (int q = 0; q < 4; ++q) {
            float v1 = 3.0e38f, v2 = 3.0e38f;
            int   i1 = 0x7fffffff, i2 = 0x7fffffff;
#pragma unroll
            for (int n = 0; n < 4; ++n) {
                int col = colBase + wn * 64 + n * 16 + r;
                float d = fmaf(-2.0f, acc[m][n][q], kn[n]);
                if (d < v1 || (d == v1 && col < i1)) {
                    v2 = v1; i2 = i1; v1 = d; i1 = col;
                } else if (d < v2 || (d == v2 && col < i2)) {
                    v2 = d; i2 = col;
                }
            }
#pragma unroll
            for (int msk = 1; msk < 16; msk <<= 1) {
                float ov1 = __shfl_xor(v1, msk, 64);
                int   oi1 = __shfl_xor(i1, msk, 64);
                float ov2 = __shfl_xor(v2, msk, 64);
                int   oi2 = __shfl_xor(i2, msk, 64);
                bool ob = (ov1 < v1) || (ov1 == v1 && oi1 < i1);
                float nbv = ob ? ov1 : v1;  int nbi = ob ? oi1 : i1;
                float c1v = ob ? ov2 : v2;  int c1i = ob ? oi2 : i2;
                float c2v = ob ? v1 : ov1;  int c2i = ob ? i1 : oi1;
                bool cb2 = (c2v < c1v) || (c2v == c1v && c2i < c1i);
                v1 = nbv; i1 = nbi;
                v2 = cb2 ? c2v : c1v; i2 = cb2 ? c2i : c1i;
            }
            if (r == 0) {
                int lrow = wm * 64 + m * 16 + g * 4 + q;   // 0..127
                mv[(wn * 128 + lrow) * 2 + 0] = v1;
                mv[(wn * 128 + lrow) * 2 + 1] = v2;
                mi[(wn * 128 + lrow) * 2 + 0] = i1;
                mi[(wn * 128 + lrow) * 2 + 1] = i2;
            }
        }
    }
    __syncthreads();

    // merge 2 wn-halves' top-2 -> per-row top-2 over 128 cols
    if (tid < 128) {
        float V1 = 3.0e38f, V2 = 3.0e38f;
        int   I1 = 0x7fffffff, I2 = 0x7fffffff;
#pragma unroll
        for (int s = 0; s < 4; ++s) {
            float d = mv[((s >> 1) * 128 + tid) * 2 + (s & 1)];
            int   ci = mi[((s >> 1) * 128 + tid) * 2 + (s & 1)];
            if (d < V1 || (d == V1 && ci < I1)) {
                V2 = V1; I2 = I1; V1 = d; I1 = ci;
            } else if (d < V2 || (d == V2 && ci < I2)) {
                V2 = d; I2 = ci;
            }
        }
        size_t o = (size_t)cb * BNR + rowBase + tid;
        pv1[o] = V1; pi1[o] = I1;
        pv2[o] = V2; pi2[o] = I2;
    }
}

// ---------------- refine: top-8 of 128 candidates, exact fp64 ----------------
// block 256 = 4 waves = 4 rows; lane l holds set l's {top1, top2}.
__global__ void refine_k(const float* __restrict__ x, const float* __restrict__ emb,
                         const float* __restrict__ pv1, const int* __restrict__ pi1,
                         const float* __restrict__ pv2, const int* __restrict__ pi2,
                         float* __restrict__ out_idx) {
    int row  = blockIdx.x * 4 + (threadIdx.x >> 6);
    int lane = threadIdx.x & 63;
    size_t off = (size_t)lane * BNR + row;
    float va = pv1[off]; int ia = pi1[off];
    float vb = pv2[off]; int ib = pi2[off];
    int cand[8];
#pragma unroll
    for (int b = 0; b < 8; ++b) {
        bool al = (va < vb) || (va == vb && ia < ib);
        float cv = al ? va : vb; int ci = al ? ia : ib;
#pragma unroll
        for (int msk = 1; msk < 64; msk <<= 1) {
            float ov = __shfl_xor(cv, msk, 64);
            int   oi = __shfl_xor(ci, msk, 64);
            if (ov < cv || (ov == cv && oi < ci)) { cv = ov; ci = oi; }
        }
        cand[b] = ci;
        // indices are globally unique -> invalidate by index
        if (ia == ci) va = 3.0e38f;
        else if (ib == ci) vb = 3.0e38f;
    }
    int gid = lane >> 3, gl = lane & 7;
    int myc = cand[gid];
    const float* qp = x + (size_t)row * C;
    const float* kp = emb + (size_t)myc * C;
    double s = 0.0;
#pragma unroll 4
    for (int j = gl * 64; j < gl * 64 + 64; j += 4) {
        float4 q4 = *(const float4*)(qp + j);
        float4 k4 = *(const float4*)(kp + j);
        double d0 = (double)q4.x - (double)k4.x;
        double d1 = (double)q4.y - (double)k4.y;
        double d2 = (double)q4.z - (double)k4.z;
        double d3 = (double)q4.w - (double)k4.w;
        s += d0 * d0 + d1 * d1 + d2 * d2 + d3 * d3;
    }
    s += __shfl_xor(s, 1, 64);
    s += __shfl_xor(s, 2, 64);
    s += __shfl_xor(s, 4, 64);
    double dv = (gl == 0) ? s : 1.0e300;
    int    di = (gl == 0) ? myc : 0x7fffffff;
#pragma unroll
    for (int msk = 8; msk < 64; msk <<= 1) {
        double ov = __shfl_xor(dv, msk, 64);
        int    oi = __shfl_xor(di, msk, 64);
        if (ov < dv || (ov == dv && oi < di)) { dv = ov; di = oi; }
    }
    if (lane == 0) out_idx[row] = (float)di;
}

// ---------------- fused onehot zero+scatter + z_st gather ----------------
// One block per row, coalesced stores. NON-TEMPORAL stores: the 537 MB
// onehot stream is write-once/never-read -- bypass L2 (write-allocate path
// caps at ~1.5 TB/s; NT path is how rocclr's big fills hit ~6.7 TB/s).
__global__ void onehot_gather_k(const float* __restrict__ emb,
                                const float* __restrict__ out_idx,
                                float* __restrict__ zst,
                                float* __restrict__ onehot) {
    const int row = blockIdx.x;
    const int tid = threadIdx.x;
    const int idx = (int)out_idx[row];

    // z_st row: 128 float4 (write-only -> NT)
    if (tid < 128) {
        const f32x4* src = (const f32x4*)(emb + (size_t)idx * C);
        f32x4* dst = (f32x4*)(zst + (size_t)row * C);
        __builtin_nontemporal_store(src[tid], &dst[tid]);
    }

    // onehot row: 2048 float4, coalesced, NT
    f32x4* orow = (f32x4*)(onehot + (size_t)row * M);
    const int hot4 = idx >> 2, hotc = idx & 3;
#pragma unroll
    for (int t = 0; t < 8; ++t) {
        int j4 = t * 256 + tid;
        f32x4 v = (f32x4)(0.0f);
        if (j4 == hot4) v[hotc] = 1.0f;
        __builtin_nontemporal_store(v, &orow[j4]);
    }
}

// ---------------- perplexity via LDS histogram ----------------
__global__ void perp_k(const float* __restrict__ out_idx, float* __restrict__ out_perp) {
    __shared__ int hist[M];
    __shared__ float red[256];
    int tid = threadIdx.x;
    for (int j = tid; j < M; j += 256) hist[j] = 0;
    __syncthreads();
    for (int j = tid; j < BNR; j += 256) atomicAdd(&hist[(int)out_idx[j]], 1);
    __syncthreads();
    float s = 0.f;
    for (int j = tid; j < M; j += 256) {
        float pb = (float)hist[j] * (1.0f / (float)BNR);
        s += pb * logf(pb + 1e-10f);
    }
    red[tid] = s; __syncthreads();
    for (int o = 128; o > 0; o >>= 1) {
        if (tid < o) red[tid] += red[tid + o];
        __syncthreads();
    }
    if (tid == 0) out_perp[0] = expf(-red[0]);
}

extern "C" void kernel_launch(void* const* d_in, const int* in_sizes, int n_in,
                              void* d_out, int out_size, void* d_ws, size_t ws_size,
                              hipStream_t stream) {
    const float* x   = (const float*)d_in[0];
    const float* emb = (const float*)d_in[1];

    float* out        = (float*)d_out;
    float* out_zst    = out;                              // 8388608
    float* out_idx    = out + (size_t)BNR * C;            // 16384
    float* out_onehot = out_idx + BNR;                    // 134217728
    float* out_perp   = out_onehot + (size_t)BNR * M;     // 1

    // scratch lives in the onehot region (overwritten by onehot_gather_k):
    u16*   x2t   = (u16*)out_onehot;                      // 16 MiB (tiled)
    u16*   e2t   = x2t + (size_t)BNR * C;                 // 8 MiB  (tiled)
    float* knorm = (float*)(e2t + (size_t)M * C);
    float* pv1   = knorm + M;                             // 4 MiB each
    float* pv2   = pv1 + (size_t)NSETS * BNR;
    int*   pi1   = (int*)(pv2 + (size_t)NSETS * BNR);
    int*   pi2   = pi1 + (size_t)NSETS * BNR;

    cvt_tile_k<<<(BNR * C / 8) / 256, 256, 0, stream>>>(x, x2t);
    cvt_tile_k<<<(M * C / 8) / 256, 256, 0, stream>>>(emb, e2t);
    knorm_k<<<64, 256, 0, stream>>>(emb, knorm);
    mfma_argmin_k<<<(BNR / BM) * (M / BN), 256, 0, stream>>>(
        x2t, e2t, knorm, pv1, pi1, pv2, pi2);
    refine_k<<<BNR / 4, 256, 0, stream>>>(x, emb, pv1, pi1, pv2, pi2, out_idx);
    onehot_gather_k<<<BNR, 256, 0, stream>>>(emb, out_idx, out_zst, out_onehot);
    perp_k<<<1, 256, 0, stream>>>(out_idx, out_perp);
}

// Round 16
// 465.881 us; speedup vs baseline: 1.2194x; 1.0291x over previous
//
#include <hip/hip_runtime.h>
#include <cstdint>
#include <cstddef>

#define BNR 16384   // b*n rows
#define C   512     // feature dim
#define M   8192    // codebook size
#define BM  128
#define BN  128
#define BK  64
#define NCH 8       // K chunks = C/BK
#define NSETS 64    // column blocks (8192/128)

#define NZERO 512            // zero-streamer blocks (dispatched first)
#define GEMM_BLOCKS 8192     // (BNR/BM)*(M/BN)
#define OH4_PER_ZB  65536    // float4 of onehot per zero block (1 MiB)

// tiled operand layout: [panel128][chunk8][kb8][row128][8 u16]
#define TILE_U16   8192      // u16 per (panel,chunk) tile
#define PANEL_U16  65536     // u16 per 128-row panel (8 chunks)

typedef float f32x4 __attribute__((ext_vector_type(4)));
typedef _Float16 f16x8 __attribute__((ext_vector_type(8)));
typedef unsigned short u16;

static __device__ __forceinline__ u16 h_bits(_Float16 h) {
    union { _Float16 h; u16 u; } x; x.h = h; return x.u;
}
static __device__ __forceinline__ void gl_lds16(const void* g, void* l) {
    __builtin_amdgcn_global_load_lds(
        (const __attribute__((address_space(1))) void*)g,
        (__attribute__((address_space(3))) void*)l, 16, 0, 0);
}

// ---------------- ||k||^2 per codebook row (exact fp32) ----------------
__global__ void knorm_k(const float* __restrict__ emb, float* __restrict__ knorm) {
    int gw   = (blockIdx.x * blockDim.x + threadIdx.x) >> 6;
    int lane = threadIdx.x & 63;
    int nw   = (gridDim.x * blockDim.x) >> 6;
    for (int row = gw; row < M; row += nw) {
        const float4* p = (const float4*)(emb + (size_t)row * C);
        float s = 0.f;
#pragma unroll
        for (int j = 0; j < 2; ++j) {
            float4 v = p[lane + 64 * j];
            s += v.x * v.x + v.y * v.y + v.z * v.z + v.w * v.w;
        }
#pragma unroll
        for (int o = 32; o > 0; o >>= 1) s += __shfl_down(s, o, 64);
        if (lane == 0) knorm[row] = s;
    }
}

// ---------------- fp32 -> fp16 hi, written in TILED layout (to d_ws) --------
__global__ void cvt_tile_k(const float* __restrict__ in, u16* __restrict__ outp) {
    int o = blockIdx.x * 256 + threadIdx.x;
    int q = o & 1023, kb = q >> 7, row = q & 127;
    int c = (o >> 10) & 7, pan = o >> 13;
    int grow = pan * BM + row;
    int k0 = c * BK + kb * 8;
    const float4* src = (const float4*)(in + (size_t)grow * C + k0);
    float4 a = src[0], b = src[1];
    u16 v[8] = { h_bits((_Float16)a.x), h_bits((_Float16)a.y),
                 h_bits((_Float16)a.z), h_bits((_Float16)a.w),
                 h_bits((_Float16)b.x), h_bits((_Float16)b.y),
                 h_bits((_Float16)b.z), h_bits((_Float16)b.w) };
    u16* dst = outp + (size_t)o * 8;
    *(ushort4*)(dst)     = *(ushort4*)(v);
    *(ushort4*)(dst + 4) = *(ushort4*)(v + 4);
}

// ---------------- MEGA kernel: onehot zero-stream + MFMA GEMM ----------------
// Blocks [0, NZERO): stream zeros over the 537 MB onehot output (NT stores,
// saturating the d_out write path from t=0 -- the ~1.6 TB/s allocation cap
// is the serial floor; hide the GEMM inside it).
// Blocks [NZERO, NZERO+GEMM_BLOCKS): unchanged m97-structure GEMM + top-2.
__global__ void mega_k(
    const u16* __restrict__ x2t, const u16* __restrict__ e2t,
    const float* __restrict__ knorm,
    float* __restrict__ pv1, int* __restrict__ pi1,
    float* __restrict__ pv2, int* __restrict__ pi2,
    float* __restrict__ onehot) {
    __shared__ __align__(16) u16 ldsA[8][128][8];   // 16 KiB
    __shared__ __align__(16) u16 ldsB[8][128][8];   // 16 KiB

    if (blockIdx.x < NZERO) {
        // ---- zero streamer: 1 MiB per block, contiguous, NT ----
        f32x4* o4 = (f32x4*)onehot;
        size_t base = (size_t)blockIdx.x * OH4_PER_ZB + threadIdx.x;
        const f32x4 z = (f32x4)(0.0f);
#pragma unroll 4
        for (int i = 0; i < OH4_PER_ZB / 256; ++i)
            __builtin_nontemporal_store(z, &o4[base + (size_t)i * 256]);
        return;
    }

    const int gid  = blockIdx.x - NZERO;
    const int tid  = threadIdx.x;
    const int lane = tid & 63;
    const int w    = tid >> 6;          // 0..3
    const int wm   = w >> 1, wn = w & 1;
    const int g    = lane >> 4, r = lane & 15;

    // bijective supertile XCD swizzle (gid-based; NZERO % 8 == 0 keeps
    // gid%8 == XCD alignment).
    const int xk = gid & 7, j = gid >> 3;
    const int stid = (j >> 6) * 8 + xk;      // 0..127
    const int p  = j & 63;
    const int rb = (stid & 15) * 8 + (p & 7);   // 0..127
    const int cb = (stid >> 4) * 8 + (p >> 3);  // 0..63
    const int rowBase = rb * BM, colBase = cb * BN;

    f32x4 acc[4][4];
#pragma unroll
    for (int m = 0; m < 4; ++m)
#pragma unroll
        for (int n = 0; n < 4; ++n) acc[m][n] = (f32x4)(0.0f);

    const u16* aT = x2t + (size_t)rb * PANEL_U16;
    const u16* bT = e2t + (size_t)cb * PANEL_U16;

#pragma unroll 1
    for (int c = 0; c < NCH; ++c) {
        if (c) __syncthreads();           // readers of previous tile done
#pragma unroll
        for (int it = 0; it < 4; ++it) {  // stage: 4 A-units + 4 B-units/thread
            int u = it * 256 + tid;
            gl_lds16(aT + (size_t)c * TILE_U16 + u * 8, (u16*)ldsA + u * 8);
            gl_lds16(bT + (size_t)c * TILE_U16 + u * 8, (u16*)ldsB + u * 8);
        }
        __syncthreads();                  // publishes DMA

#pragma unroll
        for (int ks = 0; ks < 2; ++ks) {
            const int kb = ks * 4 + g;
            f16x8 a[4], b[4];
#pragma unroll
            for (int m = 0; m < 4; ++m)
                a[m] = *(const f16x8*)&ldsA[kb][wm * 64 + m * 16 + r][0];
#pragma unroll
            for (int n = 0; n < 4; ++n)
                b[n] = *(const f16x8*)&ldsB[kb][wn * 64 + n * 16 + r][0];
#pragma unroll
            for (int m = 0; m < 4; ++m)
#pragma unroll
                for (int n = 0; n < 4; ++n)
                    acc[m][n] = __builtin_amdgcn_mfma_f32_16x16x32_f16(
                        a[m], b[n], acc[m][n], 0, 0, 0);
        }
    }
    __syncthreads();   // last ds_reads retired before LDS reuse

    // ---- epilogue: per-row top-2 over this block's 128 cols ----
    float kn[4];
#pragma unroll
    for (int n = 0; n < 4; ++n) kn[n] = knorm[colBase + wn * 64 + n * 16 + r];

    float* mv = (float*)&ldsA[0][0][0];           // [2 wn][128 row][2]
    int*   mi = (int*)(mv + 2 * 128 * 2);         // 2 KiB + 2 KiB

#pragma unroll
    for (int m = 0; m < 4; ++m) {
#pragma unroll
        for (int q = 0; q < 4; ++q) {
            float v1 = 3.0e38f, v2 = 3.0e38f;
            int   i1 = 0x7fffffff, i2 = 0x7fffffff;
#pragma unroll
            for (int n = 0; n < 4; ++n) {
                int col = colBase + wn * 64 + n * 16 + r;
                float d = fmaf(-2.0f, acc[m][n][q], kn[n]);
                if (d < v1 || (d == v1 && col < i1)) {
                    v2 = v1; i2 = i1; v1 = d; i1 = col;
                } else if (d < v2 || (d == v2 && col < i2)) {
                    v2 = d; i2 = col;
                }
            }
#pragma unroll
            for (int msk = 1; msk < 16; msk <<= 1) {
                float ov1 = __shfl_xor(v1, msk, 64);
                int   oi1 = __shfl_xor(i1, msk, 64);
                float ov2 = __shfl_xor(v2, msk, 64);
                int   oi2 = __shfl_xor(i2, msk, 64);
                bool ob = (ov1 < v1) || (ov1 == v1 && oi1 < i1);
                float nbv = ob ? ov1 : v1;  int nbi = ob ? oi1 : i1;
                float c1v = ob ? ov2 : v2;  int c1i = ob ? oi2 : i2;
                float c2v = ob ? v1 : ov1;  int c2i = ob ? i1 : oi1;
                bool cb2 = (c2v < c1v) || (c2v == c1v && c2i < c1i);
                v1 = nbv; i1 = nbi;
                v2 = cb2 ? c2v : c1v; i2 = cb2 ? c2i : c1i;
            }
            if (r == 0) {
                int lrow = wm * 64 + m * 16 + g * 4 + q;   // 0..127
                mv[(wn * 128 + lrow) * 2 + 0] = v1;
                mv[(wn * 128 + lrow) * 2 + 1] = v2;
                mi[(wn * 128 + lrow) * 2 + 0] = i1;
                mi[(wn * 128 + lrow) * 2 + 1] = i2;
            }
        }
    }
    __syncthreads();

    // merge 2 wn-halves' top-2 -> per-row top-2 over 128 cols
    if (tid < 128) {
        float V1 = 3.0e38f, V2 = 3.0e38f;
        int   I1 = 0x7fffffff, I2 = 0x7fffffff;
#pragma unroll
        for (int s = 0; s < 4; ++s) {
            float d = mv[((s >> 1) * 128 + tid) * 2 + (s & 1)];
            int   ci = mi[((s >> 1) * 128 + tid) * 2 + (s & 1)];
            if (d < V1 || (d == V1 && ci < I1)) {
                V2 = V1; I2 = I1; V1 = d; I1 = ci;
            } else if (d < V2 || (d == V2 && ci < I2)) {
                V2 = d; I2 = ci;
            }
        }
        size_t o = (size_t)cb * BNR + rowBase + tid;
        pv1[o] = V1; pi1[o] = I1;
        pv2[o] = V2; pi2[o] = I2;
    }
}

// ---------------- refine: top-8 of 128 candidates, exact fp64 ----------------
__global__ void refine_k(const float* __restrict__ x, const float* __restrict__ emb,
                         const float* __restrict__ pv1, const int* __restrict__ pi1,
                         const float* __restrict__ pv2, const int* __restrict__ pi2,
                         float* __restrict__ out_idx) {
    int row  = blockIdx.x * 4 + (threadIdx.x >> 6);
    int lane = threadIdx.x & 63;
    size_t off = (size_t)lane * BNR + row;
    float va = pv1[off]; int ia = pi1[off];
    float vb = pv2[off]; int ib = pi2[off];
    int cand[8];
#pragma unroll
    for (int b = 0; b < 8; ++b) {
        bool al = (va < vb) || (va == vb && ia < ib);
        float cv = al ? va : vb; int ci = al ? ia : ib;
#pragma unroll
        for (int msk = 1; msk < 64; msk <<= 1) {
            float ov = __shfl_xor(cv, msk, 64);
            int   oi = __shfl_xor(ci, msk, 64);
            if (ov < cv || (ov == cv && oi < ci)) { cv = ov; ci = oi; }
        }
        cand[b] = ci;
        if (ia == ci) va = 3.0e38f;
        else if (ib == ci) vb = 3.0e38f;
    }
    int gid = lane >> 3, gl = lane & 7;
    int myc = cand[gid];
    const float* qp = x + (size_t)row * C;
    const float* kp = emb + (size_t)myc * C;
    double s = 0.0;
#pragma unroll 4
    for (int j = gl * 64; j < gl * 64 + 64; j += 4) {
        float4 q4 = *(const float4*)(qp + j);
        float4 k4 = *(const float4*)(kp + j);
        double d0 = (double)q4.x - (double)k4.x;
        double d1 = (double)q4.y - (double)k4.y;
        double d2 = (double)q4.z - (double)k4.z;
        double d3 = (double)q4.w - (double)k4.w;
        s += d0 * d0 + d1 * d1 + d2 * d2 + d3 * d3;
    }
    s += __shfl_xor(s, 1, 64);
    s += __shfl_xor(s, 2, 64);
    s += __shfl_xor(s, 4, 64);
    double dv = (gl == 0) ? s : 1.0e300;
    int    di = (gl == 0) ? myc : 0x7fffffff;
#pragma unroll
    for (int msk = 8; msk < 64; msk <<= 1) {
        double ov = __shfl_xor(dv, msk, 64);
        int    oi = __shfl_xor(di, msk, 64);
        if (ov < dv || (ov == dv && oi < di)) { dv = ov; di = oi; }
    }
    if (lane == 0) out_idx[row] = (float)di;
}

// ---------------- finish: z_st gather + onehot 1.0 scatter ----------------
// grid BNR x 128. Runs after mega (zeros done) + refine (idx done).
__global__ void finish_k(const float* __restrict__ emb,
                         const float* __restrict__ out_idx,
                         float* __restrict__ zst, float* __restrict__ onehot) {
    int row = blockIdx.x;
    int idx = (int)out_idx[row];
    const f32x4* src = (const f32x4*)(emb + (size_t)idx * C);
    f32x4* dst = (f32x4*)(zst + (size_t)row * C);
    __builtin_nontemporal_store(src[threadIdx.x], &dst[threadIdx.x]);
    if (threadIdx.x == 0) onehot[(size_t)row * M + idx] = 1.0f;
}

// ---------------- perplexity via LDS histogram ----------------
__global__ void perp_k(const float* __restrict__ out_idx, float* __restrict__ out_perp) {
    __shared__ int hist[M];
    __shared__ float red[256];
    int tid = threadIdx.x;
    for (int j = tid; j < M; j += 256) hist[j] = 0;
    __syncthreads();
    for (int j = tid; j < BNR; j += 256) atomicAdd(&hist[(int)out_idx[j]], 1);
    __syncthreads();
    float s = 0.f;
    for (int j = tid; j < M; j += 256) {
        float pb = (float)hist[j] * (1.0f / (float)BNR);
        s += pb * logf(pb + 1e-10f);
    }
    red[tid] = s; __syncthreads();
    for (int o = 128; o > 0; o >>= 1) {
        if (tid < o) red[tid] += red[tid + o];
        __syncthreads();
    }
    if (tid == 0) out_perp[0] = expf(-red[0]);
}

extern "C" void kernel_launch(void* const* d_in, const int* in_sizes, int n_in,
                              void* d_out, int out_size, void* d_ws, size_t ws_size,
                              hipStream_t stream) {
    const float* x   = (const float*)d_in[0];
    const float* emb = (const float*)d_in[1];

    float* out        = (float*)d_out;
    float* out_zst    = out;                              // 8388608
    float* out_idx    = out + (size_t)BNR * C;            // 16384
    float* out_onehot = out_idx + BNR;                    // 134217728
    float* out_perp   = out_onehot + (size_t)BNR * M;     // 1

    // scratch now in d_ws (fast, coarse-grained allocation): ~41 MiB
    u16*   x2t   = (u16*)d_ws;                            // 16 MiB (tiled)
    u16*   e2t   = x2t + (size_t)BNR * C;                 // 8 MiB  (tiled)
    float* knorm = (float*)(e2t + (size_t)M * C);
    float* pv1   = knorm + M;                             // 4 MiB each
    float* pv2   = pv1 + (size_t)NSETS * BNR;
    int*   pi1   = (int*)(pv2 + (size_t)NSETS * BNR);
    int*   pi2   = pi1 + (size_t)NSETS * BNR;

    cvt_tile_k<<<(BNR * C / 8) / 256, 256, 0, stream>>>(x, x2t);
    cvt_tile_k<<<(M * C / 8) / 256, 256, 0, stream>>>(emb, e2t);
    knorm_k<<<64, 256, 0, stream>>>(emb, knorm);
    mega_k<<<NZERO + GEMM_BLOCKS, 256, 0, stream>>>(
        x2t, e2t, knorm, pv1, pi1, pv2, pi2, out_onehot);
    refine_k<<<BNR / 4, 256, 0, stream>>>(x, emb, pv1, pi1, pv2, pi2, out_idx);
    finish_k<<<BNR, 128, 0, stream>>>(emb, out_idx, out_zst, out_onehot);
    perp_k<<<1, 256, 0, stream>>>(out_idx, out_perp);
}

// Round 19
// 452.056 us; speedup vs baseline: 1.2567x; 1.0306x over previous
//
#include <hip/hip_runtime.h>
#include <cstdint>
#include <cstddef>

#define BNR 16384   // b*n rows
#define C   512     // feature dim
#define M   8192    // codebook size
#define BM  128
#define BN  128
#define BK  64
#define NCH 8       // K chunks = C/BK
#define NSETS 64    // column blocks (8192/128)

#define GEMM_BLOCKS 8192
#define NZ1 256              // mega zero blocks: rows [0, R1)
#define R1  8192
#define NZ2 128              // refine2 zero blocks: rows [R1, R2)
#define R2  10240
#define FIN_FULL 1536        // finish full-row blocks: rows [R2, 16384), 4/block
#define FIN_SCAT 40          // finish scatter blocks: rows [0, R2)

// tiled operand layout: [panel128][chunk8][kb8][row128][8 u16]
#define TILE_U16   8192
#define PANEL_U16  65536

typedef float f32x4 __attribute__((ext_vector_type(4)));
typedef _Float16 f16x8 __attribute__((ext_vector_type(8)));
typedef unsigned short u16;

static __device__ __forceinline__ u16 h_bits(_Float16 h) {
    union { _Float16 h; u16 u; } x; x.h = h; return x.u;
}
static __device__ __forceinline__ void gl_lds16(const void* g, void* l) {
    __builtin_amdgcn_global_load_lds(
        (const __attribute__((address_space(1))) void*)g,
        (__attribute__((address_space(3))) void*)l, 16, 0, 0);
}

// ---------------- prelude: cvt_x + cvt_e + knorm in one launch ----------------
static __device__ __forceinline__ void cvt_unit(const float* __restrict__ in,
                                                u16* __restrict__ outp, int o) {
    int q = o & 1023, kb = q >> 7, row = q & 127;
    int c = (o >> 10) & 7, pan = o >> 13;
    int grow = pan * BM + row;
    int k0 = c * BK + kb * 8;
    const float4* src = (const float4*)(in + (size_t)grow * C + k0);
    float4 a = src[0], b = src[1];
    u16 v[8] = { h_bits((_Float16)a.x), h_bits((_Float16)a.y),
                 h_bits((_Float16)a.z), h_bits((_Float16)a.w),
                 h_bits((_Float16)b.x), h_bits((_Float16)b.y),
                 h_bits((_Float16)b.z), h_bits((_Float16)b.w) };
    u16* dst = outp + (size_t)o * 8;
    *(ushort4*)(dst)     = *(ushort4*)(v);
    *(ushort4*)(dst + 4) = *(ushort4*)(v + 4);
}

__global__ void prelude_k(const float* __restrict__ x, const float* __restrict__ emb,
                          u16* __restrict__ x2t, u16* __restrict__ e2t,
                          float* __restrict__ knorm) {
    int b = blockIdx.x;
    if (b < 4096) { cvt_unit(x, x2t, b * 256 + threadIdx.x); return; }
    if (b < 6144) { cvt_unit(emb, e2t, (b - 4096) * 256 + threadIdx.x); return; }
    // knorm: 64 blocks -> 256 waves
    int t = (b - 6144) * 256 + threadIdx.x;
    int gw = t >> 6, lane = t & 63;
    for (int row = gw; row < M; row += 256) {
        const float4* p = (const float4*)(emb + (size_t)row * C);
        float s = 0.f;
#pragma unroll
        for (int j = 0; j < 2; ++j) {
            float4 v = p[lane + 64 * j];
            s += v.x * v.x + v.y * v.y + v.z * v.z + v.w * v.w;
        }
#pragma unroll
        for (int o = 32; o > 0; o >>= 1) s += __shfl_down(s, o, 64);
        if (lane == 0) knorm[row] = s;
    }
}

// ---------------- MEGA: onehot zeros rows [0,R1) + MFMA GEMM ----------------
__global__ void mega_k(
    const u16* __restrict__ x2t, const u16* __restrict__ e2t,
    const float* __restrict__ knorm,
    float* __restrict__ pv1, int* __restrict__ pi1,
    float* __restrict__ pv2, int* __restrict__ pi2,
    float* __restrict__ onehot) {
    __shared__ __align__(16) u16 ldsA[8][128][8];   // 16 KiB
    __shared__ __align__(16) u16 ldsB[8][128][8];   // 16 KiB

    if (blockIdx.x < NZ1) {
        // zero rows [0, R1): 32 rows (1 MiB) per block, contiguous NT stores
        f32x4* o4 = (f32x4*)onehot;
        size_t base = (size_t)blockIdx.x * 65536 + threadIdx.x;
        const f32x4 z = (f32x4)(0.0f);
#pragma unroll 4
        for (int i = 0; i < 256; ++i)
            __builtin_nontemporal_store(z, &o4[base + (size_t)i * 256]);
        return;
    }

    const int gid  = blockIdx.x - NZ1;
    const int tid  = threadIdx.x;
    const int lane = tid & 63;
    const int w    = tid >> 6;
    const int wm   = w >> 1, wn = w & 1;
    const int g    = lane >> 4, r = lane & 15;

    // bijective supertile XCD swizzle (NZ1 % 8 == 0 keeps alignment)
    const int xk = gid & 7, j = gid >> 3;
    const int stid = (j >> 6) * 8 + xk;
    const int p  = j & 63;
    const int rb = (stid & 15) * 8 + (p & 7);
    const int cb = (stid >> 4) * 8 + (p >> 3);
    const int rowBase = rb * BM, colBase = cb * BN;

    f32x4 acc[4][4];
#pragma unroll
    for (int m = 0; m < 4; ++m)
#pragma unroll
        for (int n = 0; n < 4; ++n) acc[m][n] = (f32x4)(0.0f);

    const u16* aT = x2t + (size_t)rb * PANEL_U16;
    const u16* bT = e2t + (size_t)cb * PANEL_U16;

#pragma unroll 1
    for (int c = 0; c < NCH; ++c) {
        if (c) __syncthreads();
#pragma unroll
        for (int it = 0; it < 4; ++it) {
            int u = it * 256 + tid;
            gl_lds16(aT + (size_t)c * TILE_U16 + u * 8, (u16*)ldsA + u * 8);
            gl_lds16(bT + (size_t)c * TILE_U16 + u * 8, (u16*)ldsB + u * 8);
        }
        __syncthreads();

#pragma unroll
        for (int ks = 0; ks < 2; ++ks) {
            const int kb = ks * 4 + g;
            f16x8 a[4], b[4];
#pragma unroll
            for (int m = 0; m < 4; ++m)
                a[m] = *(const f16x8*)&ldsA[kb][wm * 64 + m * 16 + r][0];
#pragma unroll
            for (int n = 0; n < 4; ++n)
                b[n] = *(const f16x8*)&ldsB[kb][wn * 64 + n * 16 + r][0];
#pragma unroll
            for (int m = 0; m < 4; ++m)
#pragma unroll
                for (int n = 0; n < 4; ++n)
                    acc[m][n] = __builtin_amdgcn_mfma_f32_16x16x32_f16(
                        a[m], b[n], acc[m][n], 0, 0, 0);
        }
    }
    __syncthreads();

    float kn[4];
#pragma unroll
    for (int n = 0; n < 4; ++n) kn[n] = knorm[colBase + wn * 64 + n * 16 + r];

    float* mv = (float*)&ldsA[0][0][0];
    int*   mi = (int*)(mv + 2 * 128 * 2);

#pragma unroll
    for (int m = 0; m < 4; ++m) {
#pragma unroll
        for (int q = 0; q < 4; ++q) {
            float v1 = 3.0e38f, v2 = 3.0e38f;
            int   i1 = 0x7fffffff, i2 = 0x7fffffff;
#pragma unroll
            for (int n = 0; n < 4; ++n) {
                int col = colBase + wn * 64 + n * 16 + r;
                float d = fmaf(-2.0f, acc[m][n][q], kn[n]);
                if (d < v1 || (d == v1 && col < i1)) {
                    v2 = v1; i2 = i1; v1 = d; i1 = col;
                } else if (d < v2 || (d == v2 && col < i2)) {
                    v2 = d; i2 = col;
                }
            }
#pragma unroll
            for (int msk = 1; msk < 16; msk <<= 1) {
                float ov1 = __shfl_xor(v1, msk, 64);
                int   oi1 = __shfl_xor(i1, msk, 64);
                float ov2 = __shfl_xor(v2, msk, 64);
                int   oi2 = __shfl_xor(i2, msk, 64);
                bool ob = (ov1 < v1) || (ov1 == v1 && oi1 < i1);
                float nbv = ob ? ov1 : v1;  int nbi = ob ? oi1 : i1;
                float c1v = ob ? ov2 : v2;  int c1i = ob ? oi2 : i2;
                float c2v = ob ? v1 : ov1;  int c2i = ob ? i1 : oi1;
                bool cb2 = (c2v < c1v) || (c2v == c1v && c2i < c1i);
                v1 = nbv; i1 = nbi;
                v2 = cb2 ? c2v : c1v; i2 = cb2 ? c2i : c1i;
            }
            if (r == 0) {
                int lrow = wm * 64 + m * 16 + g * 4 + q;
                mv[(wn * 128 + lrow) * 2 + 0] = v1;
                mv[(wn * 128 + lrow) * 2 + 1] = v2;
                mi[(wn * 128 + lrow) * 2 + 0] = i1;
                mi[(wn * 128 + lrow) * 2 + 1] = i2;
            }
        }
    }
    __syncthreads();

    if (tid < 128) {
        float V1 = 3.0e38f, V2 = 3.0e38f;
        int   I1 = 0x7fffffff, I2 = 0x7fffffff;
#pragma unroll
        for (int s = 0; s < 4; ++s) {
            float d = mv[((s >> 1) * 128 + tid) * 2 + (s & 1)];
            int   ci = mi[((s >> 1) * 128 + tid) * 2 + (s & 1)];
            if (d < V1 || (d == V1 && ci < I1)) {
                V2 = V1; I2 = I1; V1 = d; I1 = ci;
            } else if (d < V2 || (d == V2 && ci < I2)) {
                V2 = d; I2 = ci;
            }
        }
        size_t o = (size_t)cb * BNR + rowBase + tid;
        pv1[o] = V1; pi1[o] = I1;
        pv2[o] = V2; pi2[o] = I2;
    }
}

// ---------------- refine2: Z2 zeros rows [R1,R2) + refine + z_st + idx ----------
__global__ void refine2_k(const float* __restrict__ x, const float* __restrict__ emb,
                          const float* __restrict__ pv1, const int* __restrict__ pi1,
                          const float* __restrict__ pv2, const int* __restrict__ pi2,
                          float* __restrict__ out_idx, float* __restrict__ zst,
                          float* __restrict__ onehot) {
    if (blockIdx.x < NZ2) {
        // zero rows [R1, R2): 16 rows (512 KiB) per block
        f32x4* o4 = (f32x4*)onehot;
        size_t base = (size_t)R1 * 2048 + (size_t)blockIdx.x * 32768 + threadIdx.x;
        const f32x4 z = (f32x4)(0.0f);
#pragma unroll 4
        for (int i = 0; i < 128; ++i)
            __builtin_nontemporal_store(z, &o4[base + (size_t)i * 256]);
        return;
    }
    int rid  = blockIdx.x - NZ2;
    int row  = rid * 4 + (threadIdx.x >> 6);
    int lane = threadIdx.x & 63;
    size_t off = (size_t)lane * BNR + row;
    float va = pv1[off]; int ia = pi1[off];
    float vb = pv2[off]; int ib = pi2[off];
    int cand[8];
#pragma unroll
    for (int b = 0; b < 8; ++b) {
        bool al = (va < vb) || (va == vb && ia < ib);
        float cv = al ? va : vb; int ci = al ? ia : ib;
#pragma unroll
        for (int msk = 1; msk < 64; msk <<= 1) {
            float ov = __shfl_xor(cv, msk, 64);
            int   oi = __shfl_xor(ci, msk, 64);
            if (ov < cv || (ov == cv && oi < ci)) { cv = ov; ci = oi; }
        }
        cand[b] = ci;
        if (ia == ci) va = 3.0e38f;
        else if (ib == ci) vb = 3.0e38f;
    }
    int gid = lane >> 3, gl = lane & 7;
    int myc = cand[gid];
    const float* qp = x + (size_t)row * C;
    const float* kp = emb + (size_t)myc * C;
    double s = 0.0;
#pragma unroll 4
    for (int j = gl * 64; j < gl * 64 + 64; j += 4) {
        float4 q4 = *(const float4*)(qp + j);
        float4 k4 = *(const float4*)(kp + j);
        double d0 = (double)q4.x - (double)k4.x;
        double d1 = (double)q4.y - (double)k4.y;
        double d2 = (double)q4.z - (double)k4.z;
        double d3 = (double)q4.w - (double)k4.w;
        s += d0 * d0 + d1 * d1 + d2 * d2 + d3 * d3;
    }
    // intra-group sum: after masks 1,2,4 EVERY lane of the 8-lane gid-group
    // holds its candidate's full distance.
    s += __shfl_xor(s, 1, 64);
    s += __shfl_xor(s, 2, 64);
    s += __shfl_xor(s, 4, 64);
    // all-lane min-reduce over ALL masks: every lane converges to the global
    // winner (R18 bug: gl==0 gating + masks{8,16,32} left 56 lanes with
    // di=0x7fffffff -> OOB gather -> device fault).
    double dv = s; int di = myc;
#pragma unroll
    for (int msk = 1; msk < 64; msk <<= 1) {
        double ov = __shfl_xor(dv, msk, 64);
        int    oi = __shfl_xor(di, msk, 64);
        if (ov < dv || (ov == dv && oi < di)) { dv = ov; di = oi; }
    }
    // all 64 lanes now genuinely hold the winner di -> write z_st row
    const f32x4* er = (const f32x4*)(emb + (size_t)di * C);
    f32x4* zr = (f32x4*)(zst + (size_t)row * C);
    __builtin_nontemporal_store(er[lane * 2],     &zr[lane * 2]);
    __builtin_nontemporal_store(er[lane * 2 + 1], &zr[lane * 2 + 1]);
    if (lane == 0) out_idx[row] = (float)di;
}

// ---------------- finish: rows [R2,16384) full write + scatter [0,R2) ---------
__global__ void finish_k(const float* __restrict__ out_idx,
                         float* __restrict__ onehot) {
    if (blockIdx.x < FIN_FULL) {
        int base = R2 + blockIdx.x * 4;
#pragma unroll
        for (int r4 = 0; r4 < 4; ++r4) {
            int row = base + r4;
            int idx = (int)out_idx[row];
            int hot4 = idx >> 2, hotc = idx & 3;
            f32x4* orow = (f32x4*)(onehot + (size_t)row * M);
#pragma unroll
            for (int t = 0; t < 8; ++t) {
                int j4 = t * 256 + threadIdx.x;
                f32x4 v = (f32x4)(0.0f);
                if (j4 == hot4) v[hotc] = 1.0f;
                __builtin_nontemporal_store(v, &orow[j4]);
            }
        }
        return;
    }
    int gid = (blockIdx.x - FIN_FULL) * 256 + threadIdx.x;
    if (gid < R2) {
        int idx = (int)out_idx[gid];
        onehot[(size_t)gid * M + idx] = 1.0f;
    }
}

// ---------------- perplexity via LDS histogram ----------------
__global__ void perp_k(const float* __restrict__ out_idx, float* __restrict__ out_perp) {
    __shared__ int hist[M];
    __shared__ float red[256];
    int tid = threadIdx.x;
    for (int j = tid; j < M; j += 256) hist[j] = 0;
    __syncthreads();
    for (int j = tid; j < BNR; j += 256) atomicAdd(&hist[(int)out_idx[j]], 1);
    __syncthreads();
    float s = 0.f;
    for (int j = tid; j < M; j += 256) {
        float pb = (float)hist[j] * (1.0f / (float)BNR);
        s += pb * logf(pb + 1e-10f);
    }
    red[tid] = s; __syncthreads();
    for (int o = 128; o > 0; o >>= 1) {
        if (tid < o) red[tid] += red[tid + o];
        __syncthreads();
    }
    if (tid == 0) out_perp[0] = expf(-red[0]);
}

extern "C" void kernel_launch(void* const* d_in, const int* in_sizes, int n_in,
                              void* d_out, int out_size, void* d_ws, size_t ws_size,
                              hipStream_t stream) {
    const float* x   = (const float*)d_in[0];
    const float* emb = (const float*)d_in[1];

    float* out        = (float*)d_out;
    float* out_zst    = out;                              // 8388608
    float* out_idx    = out + (size_t)BNR * C;            // 16384
    float* out_onehot = out_idx + BNR;                    // 134217728
    float* out_perp   = out_onehot + (size_t)BNR * M;     // 1

    // scratch in d_ws (fast allocation): ~41 MiB
    u16*   x2t   = (u16*)d_ws;                            // 16 MiB (tiled)
    u16*   e2t   = x2t + (size_t)BNR * C;                 // 8 MiB  (tiled)
    float* knorm = (float*)(e2t + (size_t)M * C);
    float* pv1   = knorm + M;                             // 4 MiB each
    float* pv2   = pv1 + (size_t)NSETS * BNR;
    int*   pi1   = (int*)(pv2 + (size_t)NSETS * BNR);
    int*   pi2   = pi1 + (size_t)NSETS * BNR;

    prelude_k<<<6208, 256, 0, stream>>>(x, emb, x2t, e2t, knorm);
    mega_k<<<NZ1 + GEMM_BLOCKS, 256, 0, stream>>>(
        x2t, e2t, knorm, pv1, pi1, pv2, pi2, out_onehot);
    refine2_k<<<NZ2 + BNR / 4, 256, 0, stream>>>(
        x, emb, pv1, pi1, pv2, pi2, out_idx, out_zst, out_onehot);
    finish_k<<<FIN_FULL + FIN_SCAT, 256, 0, stream>>>(out_idx, out_onehot);
    perp_k<<<1, 256, 0, stream>>>(out_idx, out_perp);
}

// Round 20
// 433.717 us; speedup vs baseline: 1.3098x; 1.0423x over previous
//
#include <hip/hip_runtime.h>
#include <cstdint>
#include <cstddef>

#define BNR 16384   // b*n rows
#define C   512     // feature dim
#define M   8192    // codebook size
#define BM  128
#define BN  128
#define BK  64
#define NCH 8       // K chunks = C/BK
#define NSETS 64    // column blocks (8192/128)

#define GEMM_BLOCKS 8192
#define NZP 32               // prelude zero blocks: rows [0, RZP)
#define RZP 1024
#define NZ1 224              // mega zero blocks: rows [RZP, R1)
#define R1  8192             // rows >= R1 written whole by refine3

// tiled operand layout: [panel128][chunk8][kb8][row128][8 u16]
#define TILE_U16   8192
#define PANEL_U16  65536

typedef float f32x4 __attribute__((ext_vector_type(4)));
typedef _Float16 f16x8 __attribute__((ext_vector_type(8)));
typedef unsigned short u16;

static __device__ __forceinline__ u16 h_bits(_Float16 h) {
    union { _Float16 h; u16 u; } x; x.h = h; return x.u;
}
static __device__ __forceinline__ void gl_lds16(const void* g, void* l) {
    __builtin_amdgcn_global_load_lds(
        (const __attribute__((address_space(1))) void*)g,
        (__attribute__((address_space(3))) void*)l, 16, 0, 0);
}

// ---------------- prelude: d_out zero-start + cvt_x + cvt_e + knorm ----------
static __device__ __forceinline__ void cvt_unit(const float* __restrict__ in,
                                                u16* __restrict__ outp, int o) {
    int q = o & 1023, kb = q >> 7, row = q & 127;
    int c = (o >> 10) & 7, pan = o >> 13;
    int grow = pan * BM + row;
    int k0 = c * BK + kb * 8;
    const float4* src = (const float4*)(in + (size_t)grow * C + k0);
    float4 a = src[0], b = src[1];
    u16 v[8] = { h_bits((_Float16)a.x), h_bits((_Float16)a.y),
                 h_bits((_Float16)a.z), h_bits((_Float16)a.w),
                 h_bits((_Float16)b.x), h_bits((_Float16)b.y),
                 h_bits((_Float16)b.z), h_bits((_Float16)b.w) };
    u16* dst = outp + (size_t)o * 8;
    *(ushort4*)(dst)     = *(ushort4*)(v);
    *(ushort4*)(dst + 4) = *(ushort4*)(v + 4);
}

__global__ void prelude_k(const float* __restrict__ x, const float* __restrict__ emb,
                          u16* __restrict__ x2t, u16* __restrict__ e2t,
                          float* __restrict__ knorm, float* __restrict__ onehot) {
    int b = blockIdx.x;
    if (b < NZP) {
        // zero rows [0, RZP): 32 rows (1 MiB) per block -- starts the d_out
        // stream while cvt/knorm use the (uncapped) d_ws write path.
        f32x4* o4 = (f32x4*)onehot;
        size_t base = (size_t)b * 65536 + threadIdx.x;
        const f32x4 z = (f32x4)(0.0f);
#pragma unroll 4
        for (int i = 0; i < 256; ++i)
            __builtin_nontemporal_store(z, &o4[base + (size_t)i * 256]);
        return;
    }
    b -= NZP;
    if (b < 4096) { cvt_unit(x, x2t, b * 256 + threadIdx.x); return; }
    if (b < 6144) { cvt_unit(emb, e2t, (b - 4096) * 256 + threadIdx.x); return; }
    // knorm: 64 blocks -> 256 waves
    int t = (b - 6144) * 256 + threadIdx.x;
    int gw = t >> 6, lane = t & 63;
    for (int row = gw; row < M; row += 256) {
        const float4* p = (const float4*)(emb + (size_t)row * C);
        float s = 0.f;
#pragma unroll
        for (int j = 0; j < 2; ++j) {
            float4 v = p[lane + 64 * j];
            s += v.x * v.x + v.y * v.y + v.z * v.z + v.w * v.w;
        }
#pragma unroll
        for (int o = 32; o > 0; o >>= 1) s += __shfl_down(s, o, 64);
        if (lane == 0) knorm[row] = s;
    }
}

// ---------------- MEGA: onehot zeros rows [RZP,R1) + MFMA GEMM ----------------
__global__ void mega_k(
    const u16* __restrict__ x2t, const u16* __restrict__ e2t,
    const float* __restrict__ knorm,
    float* __restrict__ pv1, int* __restrict__ pi1,
    float* __restrict__ pv2, int* __restrict__ pi2,
    float* __restrict__ onehot) {
    __shared__ __align__(16) u16 ldsA[8][128][8];   // 16 KiB
    __shared__ __align__(16) u16 ldsB[8][128][8];   // 16 KiB

    if (blockIdx.x < NZ1) {
        // zero rows [RZP, R1): 32 rows (1 MiB) per block, contiguous NT
        f32x4* o4 = (f32x4*)onehot;
        size_t base = (size_t)RZP * 2048 + (size_t)blockIdx.x * 65536 + threadIdx.x;
        const f32x4 z = (f32x4)(0.0f);
#pragma unroll 4
        for (int i = 0; i < 256; ++i)
            __builtin_nontemporal_store(z, &o4[base + (size_t)i * 256]);
        return;
    }

    const int gid  = blockIdx.x - NZ1;
    const int tid  = threadIdx.x;
    const int lane = tid & 63;
    const int w    = tid >> 6;
    const int wm   = w >> 1, wn = w & 1;
    const int g    = lane >> 4, r = lane & 15;

    // bijective supertile XCD swizzle (NZ1 % 8 == 0 keeps alignment)
    const int xk = gid & 7, j = gid >> 3;
    const int stid = (j >> 6) * 8 + xk;
    const int p  = j & 63;
    const int rb = (stid & 15) * 8 + (p & 7);
    const int cb = (stid >> 4) * 8 + (p >> 3);
    const int rowBase = rb * BM, colBase = cb * BN;

    f32x4 acc[4][4];
#pragma unroll
    for (int m = 0; m < 4; ++m)
#pragma unroll
        for (int n = 0; n < 4; ++n) acc[m][n] = (f32x4)(0.0f);

    const u16* aT = x2t + (size_t)rb * PANEL_U16;
    const u16* bT = e2t + (size_t)cb * PANEL_U16;

#pragma unroll 1
    for (int c = 0; c < NCH; ++c) {
        if (c) __syncthreads();
#pragma unroll
        for (int it = 0; it < 4; ++it) {
            int u = it * 256 + tid;
            gl_lds16(aT + (size_t)c * TILE_U16 + u * 8, (u16*)ldsA + u * 8);
            gl_lds16(bT + (size_t)c * TILE_U16 + u * 8, (u16*)ldsB + u * 8);
        }
        __syncthreads();

#pragma unroll
        for (int ks = 0; ks < 2; ++ks) {
            const int kb = ks * 4 + g;
            f16x8 a[4], b[4];
#pragma unroll
            for (int m = 0; m < 4; ++m)
                a[m] = *(const f16x8*)&ldsA[kb][wm * 64 + m * 16 + r][0];
#pragma unroll
            for (int n = 0; n < 4; ++n)
                b[n] = *(const f16x8*)&ldsB[kb][wn * 64 + n * 16 + r][0];
#pragma unroll
            for (int m = 0; m < 4; ++m)
#pragma unroll
                for (int n = 0; n < 4; ++n)
                    acc[m][n] = __builtin_amdgcn_mfma_f32_16x16x32_f16(
                        a[m], b[n], acc[m][n], 0, 0, 0);
        }
    }
    __syncthreads();

    float kn[4];
#pragma unroll
    for (int n = 0; n < 4; ++n) kn[n] = knorm[colBase + wn * 64 + n * 16 + r];

    float* mv = (float*)&ldsA[0][0][0];
    int*   mi = (int*)(mv + 2 * 128 * 2);

#pragma unroll
    for (int m = 0; m < 4; ++m) {
#pragma unroll
        for (int q = 0; q < 4; ++q) {
            float v1 = 3.0e38f, v2 = 3.0e38f;
            int   i1 = 0x7fffffff, i2 = 0x7fffffff;
#pragma unroll
            for (int n = 0; n < 4; ++n) {
                int col = colBase + wn * 64 + n * 16 + r;
                float d = fmaf(-2.0f, acc[m][n][q], kn[n]);
                if (d < v1 || (d == v1 && col < i1)) {
                    v2 = v1; i2 = i1; v1 = d; i1 = col;
                } else if (d < v2 || (d == v2 && col < i2)) {
                    v2 = d; i2 = col;
                }
            }
#pragma unroll
            for (int msk = 1; msk < 16; msk <<= 1) {
                float ov1 = __shfl_xor(v1, msk, 64);
                int   oi1 = __shfl_xor(i1, msk, 64);
                float ov2 = __shfl_xor(v2, msk, 64);
                int   oi2 = __shfl_xor(i2, msk, 64);
                bool ob = (ov1 < v1) || (ov1 == v1 && oi1 < i1);
                float nbv = ob ? ov1 : v1;  int nbi = ob ? oi1 : i1;
                float c1v = ob ? ov2 : v2;  int c1i = ob ? oi2 : i2;
                float c2v = ob ? v1 : ov1;  int c2i = ob ? i1 : oi1;
                bool cb2 = (c2v < c1v) || (c2v == c1v && c2i < c1i);
                v1 = nbv; i1 = nbi;
                v2 = cb2 ? c2v : c1v; i2 = cb2 ? c2i : c1i;
            }
            if (r == 0) {
                int lrow = wm * 64 + m * 16 + g * 4 + q;
                mv[(wn * 128 + lrow) * 2 + 0] = v1;
                mv[(wn * 128 + lrow) * 2 + 1] = v2;
                mi[(wn * 128 + lrow) * 2 + 0] = i1;
                mi[(wn * 128 + lrow) * 2 + 1] = i2;
            }
        }
    }
    __syncthreads();

    if (tid < 128) {
        float V1 = 3.0e38f, V2 = 3.0e38f;
        int   I1 = 0x7fffffff, I2 = 0x7fffffff;
#pragma unroll
        for (int s = 0; s < 4; ++s) {
            float d = mv[((s >> 1) * 128 + tid) * 2 + (s & 1)];
            int   ci = mi[((s >> 1) * 128 + tid) * 2 + (s & 1)];
            if (d < V1 || (d == V1 && ci < I1)) {
                V2 = V1; I2 = I1; V1 = d; I1 = ci;
            } else if (d < V2 || (d == V2 && ci < I2)) {
                V2 = d; I2 = ci;
            }
        }
        size_t o = (size_t)cb * BNR + rowBase + tid;
        pv1[o] = V1; pi1[o] = I1;
        pv2[o] = V2; pi2[o] = I2;
    }
}

// ---------------- refine3: refine + z_st + idx + onehot (scatter/full) --------
// 4096 blocks x 256 threads = 4 waves, one row per wave.
// rows <  R1: onehot zeros came from prelude/mega -> scatter 1.0 only.
// rows >= R1: this wave writes the ENTIRE onehot row (zeros + 1.0 fused).
__global__ void refine3_k(const float* __restrict__ x, const float* __restrict__ emb,
                          const float* __restrict__ pv1, const int* __restrict__ pi1,
                          const float* __restrict__ pv2, const int* __restrict__ pi2,
                          float* __restrict__ out_idx, float* __restrict__ zst,
                          float* __restrict__ onehot) {
    int row  = blockIdx.x * 4 + (threadIdx.x >> 6);
    int lane = threadIdx.x & 63;
    size_t off = (size_t)lane * BNR + row;
    float va = pv1[off]; int ia = pi1[off];
    float vb = pv2[off]; int ib = pi2[off];
    int cand[8];
#pragma unroll
    for (int b = 0; b < 8; ++b) {
        bool al = (va < vb) || (va == vb && ia < ib);
        float cv = al ? va : vb; int ci = al ? ia : ib;
#pragma unroll
        for (int msk = 1; msk < 64; msk <<= 1) {
            float ov = __shfl_xor(cv, msk, 64);
            int   oi = __shfl_xor(ci, msk, 64);
            if (ov < cv || (ov == cv && oi < ci)) { cv = ov; ci = oi; }
        }
        cand[b] = ci;
        if (ia == ci) va = 3.0e38f;
        else if (ib == ci) vb = 3.0e38f;
    }
    int gid = lane >> 3, gl = lane & 7;
    int myc = cand[gid];
    const float* qp = x + (size_t)row * C;
    const float* kp = emb + (size_t)myc * C;
    double s = 0.0;
#pragma unroll 4
    for (int j = gl * 64; j < gl * 64 + 64; j += 4) {
        float4 q4 = *(const float4*)(qp + j);
        float4 k4 = *(const float4*)(kp + j);
        double d0 = (double)q4.x - (double)k4.x;
        double d1 = (double)q4.y - (double)k4.y;
        double d2 = (double)q4.z - (double)k4.z;
        double d3 = (double)q4.w - (double)k4.w;
        s += d0 * d0 + d1 * d1 + d2 * d2 + d3 * d3;
    }
    // intra-group sum (masks 1,2,4): every lane of the 8-lane group holds its
    // candidate's full distance; then ALL-mask min-reduce -> every lane holds
    // the global winner (R18 lesson: never read a reduce result from lanes
    // outside the reduce's mask subgroup).
    s += __shfl_xor(s, 1, 64);
    s += __shfl_xor(s, 2, 64);
    s += __shfl_xor(s, 4, 64);
    double dv = s; int di = myc;
#pragma unroll
    for (int msk = 1; msk < 64; msk <<= 1) {
        double ov = __shfl_xor(dv, msk, 64);
        int    oi = __shfl_xor(di, msk, 64);
        if (ov < dv || (ov == dv && oi < di)) { dv = ov; di = oi; }
    }

    // z_st row (512 floats, 2 float4/lane, NT)
    const f32x4* er = (const f32x4*)(emb + (size_t)di * C);
    f32x4* zr = (f32x4*)(zst + (size_t)row * C);
    __builtin_nontemporal_store(er[lane * 2],     &zr[lane * 2]);
    __builtin_nontemporal_store(er[lane * 2 + 1], &zr[lane * 2 + 1]);

    // onehot
    if (row >= R1) {
        f32x4* orow = (f32x4*)(onehot + (size_t)row * M);
        const int hot4 = di >> 2, hotc = di & 3;
#pragma unroll
        for (int i = 0; i < 32; ++i) {
            int j4 = i * 64 + lane;
            f32x4 v = (f32x4)(0.0f);
            if (j4 == hot4) v[hotc] = 1.0f;
            __builtin_nontemporal_store(v, &orow[j4]);
        }
    } else if (lane == 0) {
        onehot[(size_t)row * M + di] = 1.0f;
    }
    if (lane == 0) out_idx[row] = (float)di;
}

// ---------------- perplexity via LDS histogram ----------------
__global__ void perp_k(const float* __restrict__ out_idx, float* __restrict__ out_perp) {
    __shared__ int hist[M];
    __shared__ float red[256];
    int tid = threadIdx.x;
    for (int j = tid; j < M; j += 256) hist[j] = 0;
    __syncthreads();
    for (int j = tid; j < BNR; j += 256) atomicAdd(&hist[(int)out_idx[j]], 1);
    __syncthreads();
    float s = 0.f;
    for (int j = tid; j < M; j += 256) {
        float pb = (float)hist[j] * (1.0f / (float)BNR);
        s += pb * logf(pb + 1e-10f);
    }
    red[tid] = s; __syncthreads();
    for (int o = 128; o > 0; o >>= 1) {
        if (tid < o) red[tid] += red[tid + o];
        __syncthreads();
    }
    if (tid == 0) out_perp[0] = expf(-red[0]);
}

extern "C" void kernel_launch(void* const* d_in, const int* in_sizes, int n_in,
                              void* d_out, int out_size, void* d_ws, size_t ws_size,
                              hipStream_t stream) {
    const float* x   = (const float*)d_in[0];
    const float* emb = (const float*)d_in[1];

    float* out        = (float*)d_out;
    float* out_zst    = out;                              // 8388608
    float* out_idx    = out + (size_t)BNR * C;            // 16384
    float* out_onehot = out_idx + BNR;                    // 134217728
    float* out_perp   = out_onehot + (size_t)BNR * M;     // 1

    // scratch in d_ws (fast allocation): ~41 MiB
    u16*   x2t   = (u16*)d_ws;                            // 16 MiB (tiled)
    u16*   e2t   = x2t + (size_t)BNR * C;                 // 8 MiB  (tiled)
    float* knorm = (float*)(e2t + (size_t)M * C);
    float* pv1   = knorm + M;                             // 4 MiB each
    float* pv2   = pv1 + (size_t)NSETS * BNR;
    int*   pi1   = (int*)(pv2 + (size_t)NSETS * BNR);
    int*   pi2   = pi1 + (size_t)NSETS * BNR;

    prelude_k<<<NZP + 6208, 256, 0, stream>>>(x, emb, x2t, e2t, knorm, out_onehot);
    mega_k<<<NZ1 + GEMM_BLOCKS, 256, 0, stream>>>(
        x2t, e2t, knorm, pv1, pi1, pv2, pi2, out_onehot);
    refine3_k<<<BNR / 4, 256, 0, stream>>>(
        x, emb, pv1, pi1, pv2, pi2, out_idx, out_zst, out_onehot);
    perp_k<<<1, 256, 0, stream>>>(out_idx, out_perp);
}